// Round 10
// baseline (1847.498 us; speedup 1.0000x reference)
//
#include <hip/hip_runtime.h>
#include <math.h>

typedef __bf16 bf16;
typedef __bf16 bf16x8 __attribute__((ext_vector_type(8)));
typedef __bf16 bf16x2 __attribute__((ext_vector_type(2)));
typedef float  floatx4 __attribute__((ext_vector_type(4)));

// dims
#define BB 1024
#define TT 120
#define FF 32
#define DD 128
#define NROWS (BB*TT)      // 122880
#define HOR 90
#define MM 5

__device__ __forceinline__ float fast_sigmoid(float x) {
    x = fminf(fmaxf(x, -30.f), 30.f);
    return 1.f / (1.f + __expf(-x));
}
__device__ __forceinline__ float fast_tanh(float x) {
    x = fminf(fmaxf(x, -15.f), 15.f);
    float e = __expf(-2.f * x);
    return (1.f - e) / (1.f + e);
}

// hd/g1 swizzled LDS position (conflict-free b128 frag loads, proven gru5)
#define HPOS(row,d) ((row)*128 + ((((d)>>3) ^ (row)) & 15)*8 + ((d)&7))

// ---------------------------------------------------------------------------
// Encoder weights -> bf16.
__global__ __launch_bounds__(256) void prep_weights(
    const float* __restrict__ qkv, const float* __restrict__ outw,
    const float* __restrict__ f1,  const float* __restrict__ f2,
    bf16* __restrict__ dst)
{
    int i = blockIdx.x*256 + threadIdx.x;
    if (i >= 393216) return;
    float v;
    if      (i < 98304)  v = qkv[i];
    else if (i < 131072) v = outw[i - 98304];
    else if (i < 262144) v = f1[i - 131072];
    else                 v = f2[i - 262144];
    dst[i] = (bf16)v;
}

// ---------------------------------------------------------------------------
// Input projection + PE + fused ln1(L0). 4 rows/block, one wave per row.
__global__ __launch_bounds__(256) void inproj3(
    const float* __restrict__ x, const int* __restrict__ sym_id,
    const float* __restrict__ sym_emb, const float* __restrict__ in_w,
    const float* __restrict__ in_b, const float* __restrict__ lnw,
    const float* __restrict__ lnb, float* __restrict__ h, bf16* __restrict__ y)
{
    __shared__ float xin[4][48];
    const int tid = threadIdx.x, lane = tid & 63, wave = tid >> 6;
    const int row0 = blockIdx.x * 4;
    if (tid < 192) {
        int rr = tid / 48, k = tid % 48;
        int row = row0 + rr;
        int b = row / TT;
        xin[rr][k] = (k < 32) ? x[(size_t)row*FF + k]
                              : sym_emb[(size_t)sym_id[b]*16 + (k - 32)];
    }
    __syncthreads();
    const int row = row0 + wave;
    const int t = row % TT;
    const int d0 = lane*2;
    float a0 = in_b[d0], a1 = in_b[d0+1];
    const float* w0 = in_w + (size_t)d0*48;
    const float* w1 = w0 + 48;
    #pragma unroll 8
    for (int k = 0; k < 48; ++k) {
        float xv = xin[wave][k];
        a0 += xv * w0[k];
        a1 += xv * w1[k];
    }
    const float f = expf((float)d0 * (-9.210340371976184f / 128.f));
    const float arg = (float)t * f;
    a0 += sinf(arg);
    a1 += cosf(arg);
    float2 hv = {a0, a1};
    *(float2*)&h[(size_t)row*DD + d0] = hv;
    float s = a0 + a1, ss = a0*a0 + a1*a1;
    #pragma unroll
    for (int o = 1; o < 64; o <<= 1) { s += __shfl_xor(s, o); ss += __shfl_xor(ss, o); }
    float mean = s * (1.f/128.f);
    float var  = ss * (1.f/128.f) - mean*mean;
    float rstd = rsqrtf(var + 1e-5f);
    bf16x2 o2 = {(bf16)((a0 - mean)*rstd*lnw[d0]   + lnb[d0]),
                 (bf16)((a1 - mean)*rstd*lnw[d0+1] + lnb[d0+1])};
    *(bf16x2*)&y[(size_t)row*DD + d0] = o2;
}

// ---------------------------------------------------------------------------
// bf16 MFMA GEMM, BK=64 (32KB LDS -> 4 blocks/CU). Addressing proven in
// gemm_split. EPI: 0 bias->bf16, 1 bias+relu->bf16, 2 bias+res->f32,
// 3 bias+res->f32 AND fused row-LN->bf16 (N==128).
template<int EPI>
__global__ __launch_bounds__(256) void gemm64(
    const bf16* __restrict__ A, const bf16* __restrict__ W,
    const float* __restrict__ bias, const float* __restrict__ res,
    void* __restrict__ outp, const float* __restrict__ lnw,
    const float* __restrict__ lnb, bf16* __restrict__ yout, int N, int K)
{
    __shared__ alignas(16) bf16 As[128*64];
    __shared__ alignas(16) bf16 Ws[128*64];
    __shared__ float psum[2][128];
    __shared__ float psq[2][128];
    const int tid = threadIdx.x;
    const int lane = tid & 63, wave = tid >> 6;
    const int q = lane >> 4, ml = lane & 15;
    const int wm = (wave & 1) * 64, wn = (wave >> 1) * 64;
    const int m0 = blockIdx.x * 128, n0 = blockIdx.y * 128;
    floatx4 acc[4][4];
    #pragma unroll
    for (int i = 0; i < 4; ++i)
        #pragma unroll
        for (int j = 0; j < 4; ++j) acc[i][j] = (floatx4){0.f,0.f,0.f,0.f};
    const int nkb = K >> 6;
    for (int kb = 0; kb < nkb; ++kb) {
        #pragma unroll
        for (int i = 0; i < 4; ++i) {
            int idx = i*256 + tid;
            int r = idx >> 3, c = idx & 7;
            int sw = ((c ^ (r & 7)) * 8);
            *(uint4*)&As[r*64 + sw] = *(const uint4*)(A + (size_t)(m0 + r)*K + kb*64 + c*8);
            *(uint4*)&Ws[r*64 + sw] = *(const uint4*)(W + (size_t)(n0 + r)*K + kb*64 + c*8);
        }
        __syncthreads();
        #pragma unroll
        for (int s = 0; s < 2; ++s) {
            bf16x8 af[4], bfr[4];
            #pragma unroll
            for (int t = 0; t < 4; ++t) {
                int ra = wm + t*16 + ml;
                af[t]  = *(const bf16x8*)&As[ra*64 + (((s*4+q) ^ (ra & 7))*8)];
                int rb = wn + t*16 + ml;
                bfr[t] = *(const bf16x8*)&Ws[rb*64 + (((s*4+q) ^ (rb & 7))*8)];
            }
            #pragma unroll
            for (int i = 0; i < 4; ++i)
                #pragma unroll
                for (int j = 0; j < 4; ++j)
                    acc[i][j] = __builtin_amdgcn_mfma_f32_16x16x32_bf16(af[i], bfr[j], acc[i][j], 0, 0, 0);
        }
        __syncthreads();
    }
    #pragma unroll
    for (int j = 0; j < 4; ++j) {
        int col = n0 + wn + j*16 + ml;
        float bv = bias[col];
        #pragma unroll
        for (int i = 0; i < 4; ++i) {
            #pragma unroll
            for (int r = 0; r < 4; ++r) {
                int row = m0 + wm + i*16 + q*4 + r;
                size_t o = (size_t)row * N + col;
                float v = acc[i][j][r] + bv;
                if      (EPI == 0) ((bf16*)outp)[o] = (bf16)v;
                else if (EPI == 1) ((bf16*)outp)[o] = (bf16)fmaxf(v, 0.f);
                else {
                    v += res[o];
                    ((float*)outp)[o] = v;
                    acc[i][j][r] = v;
                }
            }
        }
    }
    if (EPI == 3) {
        float lw[4], lb[4];
        #pragma unroll
        for (int j = 0; j < 4; ++j) { int col = wn + j*16 + ml; lw[j] = lnw[col]; lb[j] = lnb[col]; }
        #pragma unroll
        for (int i = 0; i < 4; ++i)
            #pragma unroll
            for (int r = 0; r < 4; ++r) {
                float s  = acc[i][0][r] + acc[i][1][r] + acc[i][2][r] + acc[i][3][r];
                float ss = acc[i][0][r]*acc[i][0][r] + acc[i][1][r]*acc[i][1][r]
                         + acc[i][2][r]*acc[i][2][r] + acc[i][3][r]*acc[i][3][r];
                #pragma unroll
                for (int o = 1; o < 16; o <<= 1) { s += __shfl_xor(s, o); ss += __shfl_xor(ss, o); }
                if (ml == 0) {
                    int row = wm + i*16 + q*4 + r;
                    psum[wn >> 6][row] = s;
                    psq [wn >> 6][row] = ss;
                }
            }
        __syncthreads();
        #pragma unroll
        for (int i = 0; i < 4; ++i)
            #pragma unroll
            for (int r = 0; r < 4; ++r) {
                int row = wm + i*16 + q*4 + r;
                float mean = (psum[0][row] + psum[1][row]) * (1.f/128.f);
                float var  = (psq[0][row] + psq[1][row]) * (1.f/128.f) - mean*mean;
                float rstd = rsqrtf(var + 1e-5f);
                #pragma unroll
                for (int j = 0; j < 4; ++j) {
                    int col = wn + j*16 + ml;
                    yout[(size_t)(m0 + row)*128 + col] =
                        (bf16)((acc[i][j][r] - mean)*rstd*lw[j] + lb[j]);
                }
            }
    }
}

// ---------------------------------------------------------------------------
// bf16 MFMA attention; softmax parallelized 4 lanes/row. One block per (b,h).
__global__ __launch_bounds__(256) void attn_b16(
    const bf16* __restrict__ qkv, bf16* __restrict__ O)
{
    __shared__ alignas(16) bf16 Qs[128*32];
    __shared__ alignas(16) bf16 Ks[128*32];
    __shared__ alignas(16) bf16 VT[32*128];
    __shared__ float Sf[64*132];
    const int tid = threadIdx.x, lane = tid & 63, wave = tid >> 6;
    const int q = lane >> 4, ml = lane & 15;
    const int b = blockIdx.x >> 2, hh = blockIdx.x & 3;
    const bf16* base = qkv + (size_t)b*TT*384 + hh*32;
    #pragma unroll
    for (int i = 0; i < 2; ++i) {
        int idx = i*256 + tid;
        int r = idx >> 2, cc = idx & 3;
        uint4 vq = {0,0,0,0}, vk = {0,0,0,0};
        if (r < TT) {
            vq = *(const uint4*)(base + (size_t)r*384 + cc*8);
            vk = *(const uint4*)(base + (size_t)r*384 + 128 + cc*8);
        }
        int cs = cc ^ ((r >> 1) & 3);
        *(uint4*)&Qs[r*32 + cs*8] = vq;
        *(uint4*)&Ks[r*32 + cs*8] = vk;
    }
    #pragma unroll
    for (int i = 0; i < 16; ++i) {
        int idx = i*256 + tid;
        int t = idx >> 5, e = idx & 31;
        bf16 v = (bf16)0.f;
        if (t < TT) v = base[(size_t)t*384 + 256 + e];
        VT[e*128 + (((t >> 3) ^ (e & 15))*8) + (t & 7)] = v;
    }
    __syncthreads();
    const float scale = 0.17677669529663687f;
    for (int hf = 0; hf < 2; ++hf) {
        {
            int rowa = hf*64 + wave*16 + ml;
            bf16x8 af = *(const bf16x8*)&Qs[rowa*32 + ((q ^ ((rowa>>1)&3))*8)];
            #pragma unroll
            for (int ni = 0; ni < 8; ++ni) {
                int rowb = ni*16 + ml;
                bf16x8 bfr = *(const bf16x8*)&Ks[rowb*32 + ((q ^ ((rowb>>1)&3))*8)];
                floatx4 a4 = __builtin_amdgcn_mfma_f32_16x16x32_bf16(
                    af, bfr, (floatx4){0.f,0.f,0.f,0.f}, 0, 0, 0);
                #pragma unroll
                for (int r = 0; r < 4; ++r)
                    Sf[(wave*16 + q*4 + r)*132 + ni*16 + ml] = a4[r]*scale;
            }
        }
        __syncthreads();
        // softmax: 4 lanes per row, 30 cols each; pad cols 120..127 zeroed
        {
            int rl = wave*16 + (lane >> 2);
            int part = lane & 3;
            int rg = hf*64 + rl;
            if (rg < TT) {
                float* rowp = &Sf[rl*132 + part*30];
                float mx = -3e38f;
                #pragma unroll 10
                for (int j = 0; j < 30; ++j) mx = fmaxf(mx, rowp[j]);
                mx = fmaxf(mx, __shfl_xor(mx, 1));
                mx = fmaxf(mx, __shfl_xor(mx, 2));
                float sm = 0.f;
                #pragma unroll 10
                for (int j = 0; j < 30; ++j) sm += __expf(rowp[j] - mx);
                sm += __shfl_xor(sm, 1);
                sm += __shfl_xor(sm, 2);
                float inv = 1.f / sm;
                #pragma unroll 10
                for (int j = 0; j < 30; ++j) rowp[j] = __expf(rowp[j] - mx) * inv;
                if (part == 3) {
                    #pragma unroll
                    for (int c = 120; c < 128; ++c) Sf[rl*132 + c] = 0.f;
                }
            }
        }
        __syncthreads();
        floatx4 pacc[2];
        pacc[0] = (floatx4){0.f,0.f,0.f,0.f};
        pacc[1] = (floatx4){0.f,0.f,0.f,0.f};
        #pragma unroll
        for (int s = 0; s < 4; ++s) {
            const float* pr = &Sf[(wave*16 + ml)*132 + 32*s + 8*q];
            float4 p0 = *(const float4*)pr;
            float4 p1 = *(const float4*)(pr + 4);
            bf16x8 af2 = {(bf16)p0.x,(bf16)p0.y,(bf16)p0.z,(bf16)p0.w,
                          (bf16)p1.x,(bf16)p1.y,(bf16)p1.z,(bf16)p1.w};
            #pragma unroll
            for (int nv = 0; nv < 2; ++nv) {
                int e = nv*16 + ml;
                bf16x8 bfr = *(const bf16x8*)&VT[e*128 + ((((4*s+q) ^ (e & 15)))*8)];
                pacc[nv] = __builtin_amdgcn_mfma_f32_16x16x32_bf16(af2, bfr, pacc[nv], 0, 0, 0);
            }
        }
        #pragma unroll
        for (int nv = 0; nv < 2; ++nv)
            #pragma unroll
            for (int r = 0; r < 4; ++r) {
                int row = hf*64 + wave*16 + q*4 + r;
                if (row < TT)
                    O[((size_t)b*TT + row)*DD + hh*32 + nv*16 + ml] = (bf16)pacc[nv][r];
            }
        __syncthreads();
    }
}

// ---------------------------------------------------------------------------
// Pool+ctx+rv (proven).
__global__ __launch_bounds__(128) void pool_ctx3(
    const float* __restrict__ h, const float* __restrict__ x,
    const int* __restrict__ sym_id, const int* __restrict__ regime_id,
    const float* __restrict__ sym_emb, const float* __restrict__ reg_emb,
    const float* __restrict__ pool_w, const float* __restrict__ pool_b,
    const float* __restrict__ ctx_w, const float* __restrict__ ctx_b,
    float* __restrict__ ctxf, float* __restrict__ rv)
{
    __shared__ float sc[120];
    __shared__ float aw[120];
    __shared__ float cat[152];
    const int b = blockIdx.x;
    const int tid = threadIdx.x, lane = tid & 63, wave = tid >> 6;
    const float* hb = h + (size_t)b*TT*DD;
    for (int t = wave*60; t < wave*60 + 60; ++t) {
        const float2* hp = (const float2*)(hb + t*DD);
        float2 v = hp[lane];
        float s = v.x * pool_w[lane*2] + v.y * pool_w[lane*2 + 1];
        #pragma unroll
        for (int o = 1; o < 64; o <<= 1) s += __shfl_xor(s, o);
        if (lane == 0) sc[t] = s + pool_b[0];
    }
    __syncthreads();
    if (wave == 0) {
        float v0 = sc[lane];
        float v1 = (lane < 56) ? sc[lane + 64] : -3e38f;
        float mx = fmaxf(v0, v1);
        #pragma unroll
        for (int o = 1; o < 64; o <<= 1) mx = fmaxf(mx, __shfl_xor(mx, o));
        float e0 = expf(v0 - mx);
        float e1 = (lane < 56) ? expf(v1 - mx) : 0.f;
        float sm = e0 + e1;
        #pragma unroll
        for (int o = 1; o < 64; o <<= 1) sm += __shfl_xor(sm, o);
        float inv = 1.f / sm;
        aw[lane] = e0 * inv;
        if (lane < 56) aw[lane + 64] = e1 * inv;
    } else {
        float v0 = x[((size_t)b*TT + lane)*FF];
        float v1 = (lane < 56) ? x[((size_t)b*TT + lane + 64)*FF] : 0.f;
        float s = v0 + v1;
        #pragma unroll
        for (int o = 1; o < 64; o <<= 1) s += __shfl_xor(s, o);
        float mean = s / 120.f;
        float d0 = v0 - mean, d1 = (lane < 56) ? (v1 - mean) : 0.f;
        float ss = d0*d0 + d1*d1;
        #pragma unroll
        for (int o = 1; o < 64; o <<= 1) ss += __shfl_xor(ss, o);
        if (lane == 0) rv[b] = sqrtf(ss / 119.f);
    }
    __syncthreads();
    {
        float p = 0.f;
        for (int t = 0; t < TT; ++t) p += aw[t] * hb[(size_t)t*DD + tid];
        cat[tid] = p;
    }
    if (tid < 16)      cat[128 + tid] = sym_emb[(size_t)sym_id[b]*16 + tid];
    else if (tid < 24) cat[144 + (tid-16)] = reg_emb[regime_id[b]*8 + (tid-16)];
    __syncthreads();
    float acc = ctx_b[tid];
    const float* wr = ctx_w + (size_t)tid*152;
    for (int j = 0; j < 152; ++j) acc += cat[j] * wr[j];
    ctxf[(size_t)b*128 + tid] = acc;
}

// ---------------------------------------------------------------------------
// GRU v6: 64 blocks x 16 rows x 512 threads. 2 barriers/step:
//  PA: one hd read -> gh(st) [9 split MFMA chains] + heads(st-1) [3] + GELU -> g1
//  PB: w2 as split MFMA on g1 -> preds in regs via quad shuffles -> gate VALU -> hd
__global__ __launch_bounds__(512, 1) void gru6_kernel(
    const float* __restrict__ ctxf, const float* __restrict__ wih,
    const float* __restrict__ bih, const float* __restrict__ whh,
    const float* __restrict__ bhh,
    const float* __restrict__ mu_w1, const float* __restrict__ mu_b1,
    const float* __restrict__ mu_w2, const float* __restrict__ mu_b2,
    const float* __restrict__ vol_w1, const float* __restrict__ vol_b1,
    const float* __restrict__ vol_w2, const float* __restrict__ vol_b2,
    const float* __restrict__ rv, float* __restrict__ out)
{
    __shared__ alignas(16) bf16 hdh[16*128], hdl[16*128];
    __shared__ alignas(16) bf16 g1h[16*128], g1l[16*128];
    __shared__ float ctx_s[16*129];
    __shared__ float rvv[16];
    const int tid = threadIdx.x, lane = tid & 63, wave = tid >> 6;  // 8 waves
    const int q = lane >> 4, ml = lane & 15;
    const int col = wave*16 + ml;
    const int r0 = blockIdx.x * 16;
    const int qbase = lane & 48;             // first lane of this quad group

    // ---- weights -> split hi/lo register fragments
    bf16x8 wbh1[3][4], wbl1[3][4], wbh2[4], wbl2[4], wb3h[4], wb3l[4];
    float w50[5], w51[5], w52[5];
    #pragma unroll
    for (int g = 0; g < 3; ++g) {
        int n = g*128 + col;
        #pragma unroll
        for (int s = 0; s < 4; ++s) {
            const float* wp = whh + (size_t)n*128 + s*32 + q*8;
            float4 f0 = *(const float4*)wp;
            float4 f1 = *(const float4*)(wp + 4);
            float v[8] = {f0.x,f0.y,f0.z,f0.w,f1.x,f1.y,f1.z,f1.w};
            bf16x8 hi, lo;
            #pragma unroll
            for (int j = 0; j < 8; ++j) {
                bf16 hb = (bf16)v[j]; hi[j] = hb; lo[j] = (bf16)(v[j] - (float)hb);
            }
            wbh1[g][s] = hi; wbl1[g][s] = lo;
        }
        #pragma unroll
        for (int j = 0; j < 5; ++j) {
            float wv = wih[(size_t)n*133 + j];
            if (g == 0) w50[j] = wv; else if (g == 1) w51[j] = wv; else w52[j] = wv;
        }
    }
    const float bhh0 = bhh[col], bhh1 = bhh[128 + col], bhh2 = bhh[256 + col];
    float bias2 = (col < 64) ? mu_b1[col] : vol_b1[col - 64];
    #pragma unroll
    for (int s = 0; s < 4; ++s) {
        const float* wp = ((col < 64) ? (mu_w1 + (size_t)col*128)
                                      : (vol_w1 + (size_t)(col-64)*128)) + s*32 + q*8;
        float4 f0 = *(const float4*)wp;
        float4 f1 = *(const float4*)(wp + 4);
        float v[8] = {f0.x,f0.y,f0.z,f0.w,f1.x,f1.y,f1.z,f1.w};
        bf16x8 hi, lo;
        #pragma unroll
        for (int j = 0; j < 8; ++j) {
            bf16 hb = (bf16)v[j]; hi[j] = hb; lo[j] = (bf16)(v[j] - (float)hb);
        }
        wbh2[s] = hi; wbl2[s] = lo;
    }
    // w2 packed as B[n=ml][k]: n<5 mu head (k<64), n in 5..9 vol head (k>=64)
    #pragma unroll
    for (int s = 0; s < 4; ++s) {
        bf16x8 hi, lo;
        #pragma unroll
        for (int j = 0; j < 8; ++j) {
            int k = s*32 + q*8 + j;
            float wv = 0.f;
            if (ml < 5 && k < 64)              wv = mu_w2[ml*64 + k];
            else if (ml >= 5 && ml < 10 && k >= 64) wv = vol_w2[(ml-5)*64 + (k-64)];
            bf16 hb = (bf16)wv; hi[j] = hb; lo[j] = (bf16)(wv - (float)hb);
        }
        wb3h[s] = hi; wb3l[s] = lo;
    }
    const float b3 = (ml < 5) ? mu_b2[ml] : ((ml < 10) ? vol_b2[ml-5] : 0.f);

    // ---- init
    for (int i = tid; i < 2048; i += 512) {
        int rr = i >> 7, d = i & 127;
        float v = ctxf[(size_t)r0*128 + i];
        ctx_s[rr*129 + d] = v;
        int pos = HPOS(rr, d);
        bf16 hb = (bf16)v;
        hdh[pos] = hb;
        hdl[pos] = (bf16)(v - (float)hb);
    }
    if (tid < 16) rvv[tid] = 1.f + rv[r0 + tid];
    __syncthreads();
    // gi = bih + ctx @ wihc^T  (per-lane: 3 gates x 4 rows, fp32 exact)
    float gi0[4], gi1[4], gi2[4];
    #pragma unroll
    for (int g = 0; g < 3; ++g) {
        int n = g*128 + col;
        const float* wr = wih + (size_t)n*133 + 5;
        #pragma unroll
        for (int r = 0; r < 4; ++r) {
            int row = q*4 + r;
            float a = bih[n];
            #pragma unroll 4
            for (int k = 0; k < 128; ++k) a += ctx_s[row*129 + k] * wr[k];
            if (g == 0) gi0[r] = a; else if (g == 1) gi1[r] = a; else gi2[r] = a;
        }
    }
    __syncthreads();

    float ar[4], az[4], an[4];
    // ======= PA0: gates MFMA only (state = ctx) =======
    {
        bf16x8 ah[4], al[4];
        #pragma unroll
        for (int s = 0; s < 4; ++s) {
            int off = ml*128 + (((s*4 + q) ^ ml) & 15)*8;
            ah[s] = *(const bf16x8*)&hdh[off];
            al[s] = *(const bf16x8*)&hdl[off];
        }
        floatx4 a1={0,0,0,0},a2={0,0,0,0},a3={0,0,0,0};
        floatx4 b1={0,0,0,0},b2={0,0,0,0},b3v={0,0,0,0};
        floatx4 c1={0,0,0,0},c2={0,0,0,0},c3={0,0,0,0};
        #pragma unroll
        for (int s = 0; s < 4; ++s) {
            a1 = __builtin_amdgcn_mfma_f32_16x16x32_bf16(ah[s], wbh1[0][s], a1, 0, 0, 0);
            a2 = __builtin_amdgcn_mfma_f32_16x16x32_bf16(ah[s], wbl1[0][s], a2, 0, 0, 0);
            a3 = __builtin_amdgcn_mfma_f32_16x16x32_bf16(al[s], wbh1[0][s], a3, 0, 0, 0);
            b1 = __builtin_amdgcn_mfma_f32_16x16x32_bf16(ah[s], wbh1[1][s], b1, 0, 0, 0);
            b2 = __builtin_amdgcn_mfma_f32_16x16x32_bf16(ah[s], wbl1[1][s], b2, 0, 0, 0);
            b3v= __builtin_amdgcn_mfma_f32_16x16x32_bf16(al[s], wbh1[1][s], b3v, 0, 0, 0);
            c1 = __builtin_amdgcn_mfma_f32_16x16x32_bf16(ah[s], wbh1[2][s], c1, 0, 0, 0);
            c2 = __builtin_amdgcn_mfma_f32_16x16x32_bf16(ah[s], wbl1[2][s], c2, 0, 0, 0);
            c3 = __builtin_amdgcn_mfma_f32_16x16x32_bf16(al[s], wbh1[2][s], c3, 0, 0, 0);
        }
        #pragma unroll
        for (int r = 0; r < 4; ++r) {
            ar[r] = a1[r]+a2[r]+a3[r];
            az[r] = b1[r]+b2[r]+b3v[r];
            an[r] = c1[r]+c2[r]+c3[r];
        }
    }
    // ======= PB0: gates VALU with pred=0 =======
    #pragma unroll
    for (int r = 0; r < 4; ++r) {
        int row = q*4 + r;
        float rg = fast_sigmoid(gi0[r] + ar[r] + bhh0);
        float zg = fast_sigmoid(gi1[r] + az[r] + bhh1);
        float nn = fast_tanh(gi2[r] + rg*(an[r] + bhh2));
        int pos = HPOS(row, col);
        float hold = (float)hdh[pos] + (float)hdl[pos];
        float hnew = (1.f - zg)*nn + zg*hold;
        bf16 hb = (bf16)hnew;
        hdh[pos] = hb;
        hdl[pos] = (bf16)(hnew - (float)hb);
    }
    __syncthreads();

    for (int st = 1; st <= HOR; ++st) {
        const bool last = (st == HOR);
        // ===== PA: gh(st) [skip if last] + heads(st-1) from one hd read =====
        {
            bf16x8 ah[4], al[4];
            #pragma unroll
            for (int s = 0; s < 4; ++s) {
                int off = ml*128 + (((s*4 + q) ^ ml) & 15)*8;
                ah[s] = *(const bf16x8*)&hdh[off];
                al[s] = *(const bf16x8*)&hdl[off];
            }
            floatx4 d1={0,0,0,0},d2={0,0,0,0},d3={0,0,0,0};
            #pragma unroll
            for (int s = 0; s < 4; ++s) {
                d1 = __builtin_amdgcn_mfma_f32_16x16x32_bf16(ah[s], wbh2[s], d1, 0, 0, 0);
                d2 = __builtin_amdgcn_mfma_f32_16x16x32_bf16(ah[s], wbl2[s], d2, 0, 0, 0);
                d3 = __builtin_amdgcn_mfma_f32_16x16x32_bf16(al[s], wbh2[s], d3, 0, 0, 0);
            }
            if (!last) {
                floatx4 a1={0,0,0,0},a2={0,0,0,0},a3={0,0,0,0};
                floatx4 b1={0,0,0,0},b2={0,0,0,0},b3v={0,0,0,0};
                floatx4 c1={0,0,0,0},c2={0,0,0,0},c3={0,0,0,0};
                #pragma unroll
                for (int s = 0; s < 4; ++s) {
                    a1 = __builtin_amdgcn_mfma_f32_16x16x32_bf16(ah[s], wbh1[0][s], a1, 0, 0, 0);
                    a2 = __builtin_amdgcn_mfma_f32_16x16x32_bf16(ah[s], wbl1[0][s], a2, 0, 0, 0);
                    a3 = __builtin_amdgcn_mfma_f32_16x16x32_bf16(al[s], wbh1[0][s], a3, 0, 0, 0);
                    b1 = __builtin_amdgcn_mfma_f32_16x16x32_bf16(ah[s], wbh1[1][s], b1, 0, 0, 0);
                    b2 = __builtin_amdgcn_mfma_f32_16x16x32_bf16(ah[s], wbl1[1][s], b2, 0, 0, 0);
                    b3v= __builtin_amdgcn_mfma_f32_16x16x32_bf16(al[s], wbh1[1][s], b3v, 0, 0, 0);
                    c1 = __builtin_amdgcn_mfma_f32_16x16x32_bf16(ah[s], wbh1[2][s], c1, 0, 0, 0);
                    c2 = __builtin_amdgcn_mfma_f32_16x16x32_bf16(ah[s], wbl1[2][s], c2, 0, 0, 0);
                    c3 = __builtin_amdgcn_mfma_f32_16x16x32_bf16(al[s], wbh1[2][s], c3, 0, 0, 0);
                }
                #pragma unroll
                for (int r = 0; r < 4; ++r) {
                    ar[r] = a1[r]+a2[r]+a3[r];
                    az[r] = b1[r]+b2[r]+b3v[r];
                    an[r] = c1[r]+c2[r]+c3[r];
                }
            }
            // GELU(heads(st-1)) -> g1 hi/lo
            #pragma unroll
            for (int r = 0; r < 4; ++r) {
                float u = d1[r] + d2[r] + d3[r] + bias2;
                float g = 0.5f*u*(1.f + erff(u*0.70710678118654752f));
                int pos = HPOS(q*4 + r, col);
                bf16 hb = (bf16)g;
                g1h[pos] = hb;
                g1l[pos] = (bf16)(g - (float)hb);
            }
        }
        __syncthreads();
        // ===== PB: w2 MFMA -> preds -> out(st-1); gates VALU -> hd [skip if last]
        {
            bf16x8 gh8[4], gl8[4];
            #pragma unroll
            for (int s = 0; s < 4; ++s) {
                int off = ml*128 + (((s*4 + q) ^ ml) & 15)*8;
                gh8[s] = *(const bf16x8*)&g1h[off];
                gl8[s] = *(const bf16x8*)&g1l[off];
            }
            floatx4 e1={0,0,0,0},e2={0,0,0,0},e3={0,0,0,0};
            #pragma unroll
            for (int s = 0; s < 4; ++s) {
                e1 = __builtin_amdgcn_mfma_f32_16x16x32_bf16(gh8[s], wb3h[s], e1, 0, 0, 0);
                e2 = __builtin_amdgcn_mfma_f32_16x16x32_bf16(gh8[s], wb3l[s], e2, 0, 0, 0);
                e3 = __builtin_amdgcn_mfma_f32_16x16x32_bf16(gl8[s], wb3h[s], e3, 0, 0, 0);
            }
            float act[4];
            #pragma unroll
            for (int r = 0; r < 4; ++r) {
                float pre = e1[r] + e2[r] + e3[r] + b3;
                if (ml < 5) act[r] = tanhf(pre);
                else {
                    float sp = (pre > 20.f) ? pre : log1pf(expf(pre));
                    act[r] = sp * rvv[q*4 + r];
                }
            }
            // preds via quad shuffles (all lanes active)
            float pj[4][5];
            #pragma unroll
            for (int r = 0; r < 4; ++r) {
                #pragma unroll
                for (int j = 0; j < 5; ++j) {
                    float muj = __shfl(act[r], qbase + j);
                    float sgj = __shfl(act[r], qbase + j + 5);
                    pj[r][j] = muj * sgj;
                }
            }
            if (wave == 0 && ml < 5) {
                #pragma unroll
                for (int r = 0; r < 4; ++r)
                    out[((size_t)(r0 + q*4 + r)*HOR + (st-1))*MM + ml] = pj[r][ml >= 5 ? 0 : ml];
            }
            if (!last) {
                #pragma unroll
                for (int r = 0; r < 4; ++r) {
                    int row = q*4 + r;
                    float ir = gi0[r], iz = gi1[r], in_ = gi2[r];
                    #pragma unroll
                    for (int j = 0; j < 5; ++j) {
                        ir  += pj[r][j] * w50[j];
                        iz  += pj[r][j] * w51[j];
                        in_ += pj[r][j] * w52[j];
                    }
                    float rg = fast_sigmoid(ir + ar[r] + bhh0);
                    float zg = fast_sigmoid(iz + az[r] + bhh1);
                    float nn = fast_tanh(in_ + rg*(an[r] + bhh2));
                    int pos = HPOS(row, col);
                    float hold = (float)hdh[pos] + (float)hdl[pos];
                    float hnew = (1.f - zg)*nn + zg*hold;
                    bf16 hb = (bf16)hnew;
                    hdh[pos] = hb;
                    hdl[pos] = (bf16)(hnew - (float)hb);
                }
            }
        }
        __syncthreads();
    }
}

// ---------------------------------------------------------------------------
extern "C" void kernel_launch(void* const* d_in, const int* in_sizes, int n_in,
                              void* d_out, int out_size, void* d_ws, size_t ws_size,
                              hipStream_t stream)
{
    (void)in_sizes; (void)n_in; (void)out_size;
    const float* x        = (const float*)d_in[0];
    const int*   sym_id   = (const int*)d_in[1];
    const int*   regime_id= (const int*)d_in[2];
    const float* sym_emb  = (const float*)d_in[3];
    const float* reg_emb  = (const float*)d_in[4];
    const float* in_w     = (const float*)d_in[5];
    const float* in_b     = (const float*)d_in[6];
    const float* qkv_w    = (const float*)d_in[7];
    const float* qkv_b    = (const float*)d_in[8];
    const float* out_w    = (const float*)d_in[9];
    const float* out_bv   = (const float*)d_in[10];
    const float* ln1_w    = (const float*)d_in[11];
    const float* ln1_b    = (const float*)d_in[12];
    const float* ln2_w    = (const float*)d_in[13];
    const float* ln2_b    = (const float*)d_in[14];
    const float* f1_w     = (const float*)d_in[15];
    const float* f1_b     = (const float*)d_in[16];
    const float* f2_w     = (const float*)d_in[17];
    const float* f2_b     = (const float*)d_in[18];
    const float* pool_w   = (const float*)d_in[19];
    const float* pool_b   = (const float*)d_in[20];
    const float* ctx_w    = (const float*)d_in[21];
    const float* ctx_b    = (const float*)d_in[22];
    const float* gru_wih  = (const float*)d_in[23];
    const float* gru_whh  = (const float*)d_in[24];
    const float* gru_bih  = (const float*)d_in[25];
    const float* gru_bhh  = (const float*)d_in[26];
    const float* mu_w1    = (const float*)d_in[27];
    const float* mu_b1    = (const float*)d_in[28];
    const float* mu_w2    = (const float*)d_in[29];
    const float* mu_b2    = (const float*)d_in[30];
    const float* vol_w1   = (const float*)d_in[31];
    const float* vol_b1   = (const float*)d_in[32];
    const float* vol_w2   = (const float*)d_in[33];
    const float* vol_b2   = (const float*)d_in[34];
    float* outp = (float*)d_out;

    char* ws = (char*)d_ws;
    size_t off = 0;
    auto alloc = [&](size_t bytes) -> void* {
        void* p = ws + off;
        off = (off + bytes + 255) & ~(size_t)255;
        return p;
    };
    float* h    = (float*)alloc((size_t)NROWS*DD*4);
    bf16*  y    = (bf16*) alloc((size_t)NROWS*DD*2);
    bf16*  wbf  = (bf16*) alloc((size_t)393216*2);
    float* ctxf = (float*)alloc((size_t)BB*DD*4);
    float* rv   = (float*)alloc((size_t)BB*4);
    size_t avail = (ws_size > off) ? (ws_size - off) : 0;
    int nch;
    if      (avail >= (size_t)NROWS*512*2)     nch = 1;
    else if (avail >= (size_t)NROWS/2*512*2)   nch = 2;
    else                                       nch = 4;
    const int RC = NROWS / nch;
    const int BC = BB / nch;
    bf16* big = (bf16*)(ws + off);

    prep_weights<<<1536, 256, 0, stream>>>(qkv_w, out_w, f1_w, f2_w, wbf);
    inproj3<<<NROWS/4, 256, 0, stream>>>(x, sym_id, sym_emb, in_w, in_b,
                                         ln1_w, ln1_b, h, y);

    for (int l = 0; l < 2; ++l) {
        const bf16* wqkv = wbf + l*49152;
        const bf16* wout = wbf + 98304 + l*16384;
        const bf16* wf1  = wbf + 131072 + l*65536;
        const bf16* wf2  = wbf + 262144 + l*65536;
        for (int c = 0; c < nch; ++c) {
            const size_t ro = (size_t)c*RC;
            gemm64<0><<<dim3(RC/128, 3), 256, 0, stream>>>(
                y + ro*DD, wqkv, qkv_b + l*384, nullptr, big,
                nullptr, nullptr, nullptr, 384, 128);
            attn_b16<<<BC*4, 256, 0, stream>>>(big, y + ro*DD);
        }
        gemm64<3><<<dim3(NROWS/128, 1), 256, 0, stream>>>(
            y, wout, out_bv + l*128, h, h, ln2_w + l*128, ln2_b + l*128, y, 128, 128);
        for (int c = 0; c < nch; ++c) {
            const size_t ro = (size_t)c*RC;
            gemm64<1><<<dim3(RC/128, 4), 256, 0, stream>>>(
                y + ro*DD, wf1, f1_b + l*512, nullptr, big,
                nullptr, nullptr, nullptr, 512, 128);
            if (l == 0)
                gemm64<3><<<dim3(RC/128, 1), 256, 0, stream>>>(
                    big, wf2, f2_b + l*128, h + ro*DD, h + ro*DD,
                    ln1_w + 128, ln1_b + 128, y + ro*DD, 128, 512);
            else
                gemm64<2><<<dim3(RC/128, 1), 256, 0, stream>>>(
                    big, wf2, f2_b + l*128, h + ro*DD, h + ro*DD,
                    nullptr, nullptr, nullptr, 128, 512);
        }
    }

    pool_ctx3<<<BB, 128, 0, stream>>>(h, x, sym_id, regime_id, sym_emb, reg_emb,
                                      pool_w, pool_b, ctx_w, ctx_b, ctxf, rv);
    gru6_kernel<<<64, 512, 0, stream>>>(ctxf, gru_wih, gru_bih, gru_whh, gru_bhh,
                                        mu_w1, mu_b1, mu_w2, mu_b2,
                                        vol_w1, vol_b1, vol_w2, vol_b2,
                                        rv, outp);
}

// Round 11
// 1491.244 us; speedup vs baseline: 1.2389x; 1.2389x over previous
//
#include <hip/hip_runtime.h>
#include <math.h>

typedef __bf16 bf16;
typedef __bf16 bf16x8 __attribute__((ext_vector_type(8)));
typedef __bf16 bf16x2 __attribute__((ext_vector_type(2)));
typedef float  floatx4 __attribute__((ext_vector_type(4)));

// dims
#define BB 1024
#define TT 120
#define FF 32
#define DD 128
#define NROWS (BB*TT)      // 122880
#define HOR 90
#define MM 5

__device__ __forceinline__ float fast_sigmoid(float x) {
    x = fminf(fmaxf(x, -30.f), 30.f);
    return 1.f / (1.f + __expf(-x));
}
__device__ __forceinline__ float fast_tanh(float x) {
    x = fminf(fmaxf(x, -15.f), 15.f);
    float e = __expf(-2.f * x);
    return (1.f - e) / (1.f + e);
}

// ---------------------------------------------------------------------------
// Encoder weights -> bf16.
__global__ __launch_bounds__(256) void prep_weights(
    const float* __restrict__ qkv, const float* __restrict__ outw,
    const float* __restrict__ f1,  const float* __restrict__ f2,
    bf16* __restrict__ dst)
{
    int i = blockIdx.x*256 + threadIdx.x;
    if (i >= 393216) return;
    float v;
    if      (i < 98304)  v = qkv[i];
    else if (i < 131072) v = outw[i - 98304];
    else if (i < 262144) v = f1[i - 131072];
    else                 v = f2[i - 262144];
    dst[i] = (bf16)v;
}

// ---------------------------------------------------------------------------
// Input projection + PE + fused ln1(L0). 4 rows/block, one wave per row.
__global__ __launch_bounds__(256) void inproj3(
    const float* __restrict__ x, const int* __restrict__ sym_id,
    const float* __restrict__ sym_emb, const float* __restrict__ in_w,
    const float* __restrict__ in_b, const float* __restrict__ lnw,
    const float* __restrict__ lnb, float* __restrict__ h, bf16* __restrict__ y)
{
    __shared__ float xin[4][48];
    const int tid = threadIdx.x, lane = tid & 63, wave = tid >> 6;
    const int row0 = blockIdx.x * 4;
    if (tid < 192) {
        int rr = tid / 48, k = tid % 48;
        int row = row0 + rr;
        int b = row / TT;
        xin[rr][k] = (k < 32) ? x[(size_t)row*FF + k]
                              : sym_emb[(size_t)sym_id[b]*16 + (k - 32)];
    }
    __syncthreads();
    const int row = row0 + wave;
    const int t = row % TT;
    const int d0 = lane*2;
    float a0 = in_b[d0], a1 = in_b[d0+1];
    const float* w0 = in_w + (size_t)d0*48;
    const float* w1 = w0 + 48;
    #pragma unroll 8
    for (int k = 0; k < 48; ++k) {
        float xv = xin[wave][k];
        a0 += xv * w0[k];
        a1 += xv * w1[k];
    }
    const float f = expf((float)d0 * (-9.210340371976184f / 128.f));
    const float arg = (float)t * f;
    a0 += sinf(arg);
    a1 += cosf(arg);
    float2 hv = {a0, a1};
    *(float2*)&h[(size_t)row*DD + d0] = hv;
    float s = a0 + a1, ss = a0*a0 + a1*a1;
    #pragma unroll
    for (int o = 1; o < 64; o <<= 1) { s += __shfl_xor(s, o); ss += __shfl_xor(ss, o); }
    float mean = s * (1.f/128.f);
    float var  = ss * (1.f/128.f) - mean*mean;
    float rstd = rsqrtf(var + 1e-5f);
    bf16x2 o2 = {(bf16)((a0 - mean)*rstd*lnw[d0]   + lnb[d0]),
                 (bf16)((a1 - mean)*rstd*lnw[d0+1] + lnb[d0+1])};
    *(bf16x2*)&y[(size_t)row*DD + d0] = o2;
}

// ---------------------------------------------------------------------------
// bf16 MFMA GEMM, BK=64 (proven R10). EPI: 0 bias->bf16, 1 bias+relu->bf16,
// 2 bias+res->f32, 3 bias+res->f32 AND fused row-LN->bf16 (N==128).
template<int EPI>
__global__ __launch_bounds__(256) void gemm64(
    const bf16* __restrict__ A, const bf16* __restrict__ W,
    const float* __restrict__ bias, const float* __restrict__ res,
    void* __restrict__ outp, const float* __restrict__ lnw,
    const float* __restrict__ lnb, bf16* __restrict__ yout, int N, int K)
{
    __shared__ alignas(16) bf16 As[128*64];
    __shared__ alignas(16) bf16 Ws[128*64];
    __shared__ float psum[2][128];
    __shared__ float psq[2][128];
    const int tid = threadIdx.x;
    const int lane = tid & 63, wave = tid >> 6;
    const int q = lane >> 4, ml = lane & 15;
    const int wm = (wave & 1) * 64, wn = (wave >> 1) * 64;
    const int m0 = blockIdx.x * 128, n0 = blockIdx.y * 128;
    floatx4 acc[4][4];
    #pragma unroll
    for (int i = 0; i < 4; ++i)
        #pragma unroll
        for (int j = 0; j < 4; ++j) acc[i][j] = (floatx4){0.f,0.f,0.f,0.f};
    const int nkb = K >> 6;
    for (int kb = 0; kb < nkb; ++kb) {
        #pragma unroll
        for (int i = 0; i < 4; ++i) {
            int idx = i*256 + tid;
            int r = idx >> 3, c = idx & 7;
            int sw = ((c ^ (r & 7)) * 8);
            *(uint4*)&As[r*64 + sw] = *(const uint4*)(A + (size_t)(m0 + r)*K + kb*64 + c*8);
            *(uint4*)&Ws[r*64 + sw] = *(const uint4*)(W + (size_t)(n0 + r)*K + kb*64 + c*8);
        }
        __syncthreads();
        #pragma unroll
        for (int s = 0; s < 2; ++s) {
            bf16x8 af[4], bfr[4];
            #pragma unroll
            for (int t = 0; t < 4; ++t) {
                int ra = wm + t*16 + ml;
                af[t]  = *(const bf16x8*)&As[ra*64 + (((s*4+q) ^ (ra & 7))*8)];
                int rb = wn + t*16 + ml;
                bfr[t] = *(const bf16x8*)&Ws[rb*64 + (((s*4+q) ^ (rb & 7))*8)];
            }
            #pragma unroll
            for (int i = 0; i < 4; ++i)
                #pragma unroll
                for (int j = 0; j < 4; ++j)
                    acc[i][j] = __builtin_amdgcn_mfma_f32_16x16x32_bf16(af[i], bfr[j], acc[i][j], 0, 0, 0);
        }
        __syncthreads();
    }
    #pragma unroll
    for (int j = 0; j < 4; ++j) {
        int col = n0 + wn + j*16 + ml;
        float bv = bias[col];
        #pragma unroll
        for (int i = 0; i < 4; ++i) {
            #pragma unroll
            for (int r = 0; r < 4; ++r) {
                int row = m0 + wm + i*16 + q*4 + r;
                size_t o = (size_t)row * N + col;
                float v = acc[i][j][r] + bv;
                if      (EPI == 0) ((bf16*)outp)[o] = (bf16)v;
                else if (EPI == 1) ((bf16*)outp)[o] = (bf16)fmaxf(v, 0.f);
                else {
                    v += res[o];
                    ((float*)outp)[o] = v;
                    acc[i][j][r] = v;
                }
            }
        }
    }
    if (EPI == 3) {
        float lw[4], lb[4];
        #pragma unroll
        for (int j = 0; j < 4; ++j) { int col = wn + j*16 + ml; lw[j] = lnw[col]; lb[j] = lnb[col]; }
        #pragma unroll
        for (int i = 0; i < 4; ++i)
            #pragma unroll
            for (int r = 0; r < 4; ++r) {
                float s  = acc[i][0][r] + acc[i][1][r] + acc[i][2][r] + acc[i][3][r];
                float ss = acc[i][0][r]*acc[i][0][r] + acc[i][1][r]*acc[i][1][r]
                         + acc[i][2][r]*acc[i][2][r] + acc[i][3][r]*acc[i][3][r];
                #pragma unroll
                for (int o = 1; o < 16; o <<= 1) { s += __shfl_xor(s, o); ss += __shfl_xor(ss, o); }
                if (ml == 0) {
                    int row = wm + i*16 + q*4 + r;
                    psum[wn >> 6][row] = s;
                    psq [wn >> 6][row] = ss;
                }
            }
        __syncthreads();
        #pragma unroll
        for (int i = 0; i < 4; ++i)
            #pragma unroll
            for (int r = 0; r < 4; ++r) {
                int row = wm + i*16 + q*4 + r;
                float mean = (psum[0][row] + psum[1][row]) * (1.f/128.f);
                float var  = (psq[0][row] + psq[1][row]) * (1.f/128.f) - mean*mean;
                float rstd = rsqrtf(var + 1e-5f);
                #pragma unroll
                for (int j = 0; j < 4; ++j) {
                    int col = wn + j*16 + ml;
                    yout[(size_t)(m0 + row)*128 + col] =
                        (bf16)((acc[i][j][r] - mean)*rstd*lw[j] + lb[j]);
                }
            }
    }
}

// ---------------------------------------------------------------------------
// Fused FFN: h += W2 @ relu(W1 @ y + b1) + b2 per 64-row tile; mid in LDS.
// LNFUSE=1: also emit y = rowLN(h) (ln1 of next layer). Patterns: gemm_kernel
// K=128 staging/swizzle (proven R8/R9).
template<int LNFUSE>
__global__ __launch_bounds__(256) void ffn_fused(
    const bf16* __restrict__ y, const bf16* __restrict__ W1,
    const float* __restrict__ b1, const bf16* __restrict__ W2,
    const float* __restrict__ b2, float* __restrict__ h,
    const float* __restrict__ lnw, const float* __restrict__ lnb,
    bf16* __restrict__ yout)
{
    __shared__ alignas(16) bf16 ys[64*128];      // 16KB  A for ffn1
    __shared__ alignas(16) bf16 mid[4][64*128];  // 64KB  relu out / A for ffn2
    __shared__ alignas(16) bf16 wbuf[128*128];   // 32KB  staged W tile
    const int tid = threadIdx.x;
    const int lane = tid & 63, wave = tid >> 6;   // 4 waves
    const int q = lane >> 4, ml = lane & 15;
    const int wm = wave * 16;                     // 16 rows per wave
    const int m0 = blockIdx.x * 64;
    // stage y rows (64 x 128) swizzled like gemm_kernel As
    #pragma unroll
    for (int i = 0; i < 4; ++i) {
        int idx = i*256 + tid;
        int r = idx >> 4, cc = idx & 15;
        *(uint4*)&ys[r*128 + ((cc ^ (r & 15))*8)] =
            *(const uint4*)(y + (size_t)(m0 + r)*128 + cc*8);
    }
    __syncthreads();
    // ---- phase 1: mid = relu(ys @ W1^T + b1), 4 x 128-col blocks
    for (int nb = 0; nb < 4; ++nb) {
        #pragma unroll
        for (int i = 0; i < 8; ++i) {
            int idx = i*256 + tid;
            int r = idx >> 4, cc = idx & 15;
            *(uint4*)&wbuf[r*128 + ((cc ^ (r & 15))*8)] =
                *(const uint4*)(W1 + (size_t)(nb*128 + r)*128 + cc*8);
        }
        __syncthreads();
        bf16x8 af[4];
        #pragma unroll
        for (int s = 0; s < 4; ++s) {
            int ra = wm + ml;
            af[s] = *(const bf16x8*)&ys[ra*128 + (((4*s+q) ^ (ra & 15))*8)];
        }
        #pragma unroll
        for (int j = 0; j < 8; ++j) {
            floatx4 acc = (floatx4){0.f,0.f,0.f,0.f};
            #pragma unroll
            for (int s = 0; s < 4; ++s) {
                int rb = j*16 + ml;
                bf16x8 bfr = *(const bf16x8*)&wbuf[rb*128 + (((4*s+q) ^ (rb & 15))*8)];
                acc = __builtin_amdgcn_mfma_f32_16x16x32_bf16(af[s], bfr, acc, 0, 0, 0);
            }
            int col = j*16 + ml;
            float bv = b1[nb*128 + col];
            #pragma unroll
            for (int r = 0; r < 4; ++r) {
                int row = wm + q*4 + r;
                float v = fmaxf(acc[r] + bv, 0.f);
                mid[nb][row*128 + (((col>>3) ^ (row & 15))*8) + (col & 7)] = (bf16)v;
            }
        }
        __syncthreads();
    }
    // ---- phase 2: out = mid @ W2^T + b2 (+h) ; acc persists across kb
    floatx4 acc2[8];
    #pragma unroll
    for (int j = 0; j < 8; ++j) acc2[j] = (floatx4){0.f,0.f,0.f,0.f};
    for (int kb = 0; kb < 4; ++kb) {
        #pragma unroll
        for (int i = 0; i < 8; ++i) {
            int idx = i*256 + tid;
            int r = idx >> 4, cc = idx & 15;
            *(uint4*)&wbuf[r*128 + ((cc ^ (r & 15))*8)] =
                *(const uint4*)(W2 + (size_t)r*512 + kb*128 + cc*8);
        }
        __syncthreads();
        bf16x8 af[4];
        #pragma unroll
        for (int s = 0; s < 4; ++s) {
            int ra = wm + ml;
            af[s] = *(const bf16x8*)&mid[kb][ra*128 + (((4*s+q) ^ (ra & 15))*8)];
        }
        #pragma unroll
        for (int j = 0; j < 8; ++j) {
            #pragma unroll
            for (int s = 0; s < 4; ++s) {
                int rb = j*16 + ml;
                bf16x8 bfr = *(const bf16x8*)&wbuf[rb*128 + (((4*s+q) ^ (rb & 15))*8)];
                acc2[j] = __builtin_amdgcn_mfma_f32_16x16x32_bf16(af[s], bfr, acc2[j], 0, 0, 0);
            }
        }
        __syncthreads();
    }
    // ---- epilogue: residual, h write, optional fused LN -> yout
    float vr[8][4];
    #pragma unroll
    for (int j = 0; j < 8; ++j) {
        int col = j*16 + ml;
        float bv = b2[col];
        #pragma unroll
        for (int r = 0; r < 4; ++r) {
            int row = wm + q*4 + r;
            size_t o = (size_t)(m0 + row)*128 + col;
            float v = acc2[j][r] + bv + h[o];
            h[o] = v;
            vr[j][r] = v;
        }
    }
    if (LNFUSE) {
        float lw[8], lb[8];
        #pragma unroll
        for (int j = 0; j < 8; ++j) { lw[j] = lnw[j*16 + ml]; lb[j] = lnb[j*16 + ml]; }
        #pragma unroll
        for (int r = 0; r < 4; ++r) {
            float s = 0.f, ss = 0.f;
            #pragma unroll
            for (int j = 0; j < 8; ++j) { s += vr[j][r]; ss += vr[j][r]*vr[j][r]; }
            #pragma unroll
            for (int o = 1; o < 16; o <<= 1) { s += __shfl_xor(s, o); ss += __shfl_xor(ss, o); }
            float mean = s * (1.f/128.f);
            float var  = ss * (1.f/128.f) - mean*mean;
            float rstd = rsqrtf(var + 1e-5f);
            int row = wm + q*4 + r;
            #pragma unroll
            for (int j = 0; j < 8; ++j)
                yout[(size_t)(m0 + row)*128 + j*16 + ml] =
                    (bf16)((vr[j][r] - mean)*rstd*lw[j] + lb[j]);
        }
    }
}

// ---------------------------------------------------------------------------
// bf16 MFMA attention; softmax 4 lanes/row (proven R10). One block per (b,h).
__global__ __launch_bounds__(256) void attn_b16(
    const bf16* __restrict__ qkv, bf16* __restrict__ O)
{
    __shared__ alignas(16) bf16 Qs[128*32];
    __shared__ alignas(16) bf16 Ks[128*32];
    __shared__ alignas(16) bf16 VT[32*128];
    __shared__ float Sf[64*132];
    const int tid = threadIdx.x, lane = tid & 63, wave = tid >> 6;
    const int q = lane >> 4, ml = lane & 15;
    const int b = blockIdx.x >> 2, hh = blockIdx.x & 3;
    const bf16* base = qkv + (size_t)b*TT*384 + hh*32;
    #pragma unroll
    for (int i = 0; i < 2; ++i) {
        int idx = i*256 + tid;
        int r = idx >> 2, cc = idx & 3;
        uint4 vq = {0,0,0,0}, vk = {0,0,0,0};
        if (r < TT) {
            vq = *(const uint4*)(base + (size_t)r*384 + cc*8);
            vk = *(const uint4*)(base + (size_t)r*384 + 128 + cc*8);
        }
        int cs = cc ^ ((r >> 1) & 3);
        *(uint4*)&Qs[r*32 + cs*8] = vq;
        *(uint4*)&Ks[r*32 + cs*8] = vk;
    }
    #pragma unroll
    for (int i = 0; i < 16; ++i) {
        int idx = i*256 + tid;
        int t = idx >> 5, e = idx & 31;
        bf16 v = (bf16)0.f;
        if (t < TT) v = base[(size_t)t*384 + 256 + e];
        VT[e*128 + (((t >> 3) ^ (e & 15))*8) + (t & 7)] = v;
    }
    __syncthreads();
    const float scale = 0.17677669529663687f;
    for (int hf = 0; hf < 2; ++hf) {
        {
            int rowa = hf*64 + wave*16 + ml;
            bf16x8 af = *(const bf16x8*)&Qs[rowa*32 + ((q ^ ((rowa>>1)&3))*8)];
            #pragma unroll
            for (int ni = 0; ni < 8; ++ni) {
                int rowb = ni*16 + ml;
                bf16x8 bfr = *(const bf16x8*)&Ks[rowb*32 + ((q ^ ((rowb>>1)&3))*8)];
                floatx4 a4 = __builtin_amdgcn_mfma_f32_16x16x32_bf16(
                    af, bfr, (floatx4){0.f,0.f,0.f,0.f}, 0, 0, 0);
                #pragma unroll
                for (int r = 0; r < 4; ++r)
                    Sf[(wave*16 + q*4 + r)*132 + ni*16 + ml] = a4[r]*scale;
            }
        }
        __syncthreads();
        {
            int rl = wave*16 + (lane >> 2);
            int part = lane & 3;
            int rg = hf*64 + rl;
            if (rg < TT) {
                float* rowp = &Sf[rl*132 + part*30];
                float mx = -3e38f;
                #pragma unroll 10
                for (int j = 0; j < 30; ++j) mx = fmaxf(mx, rowp[j]);
                mx = fmaxf(mx, __shfl_xor(mx, 1));
                mx = fmaxf(mx, __shfl_xor(mx, 2));
                float sm = 0.f;
                #pragma unroll 10
                for (int j = 0; j < 30; ++j) sm += __expf(rowp[j] - mx);
                sm += __shfl_xor(sm, 1);
                sm += __shfl_xor(sm, 2);
                float inv = 1.f / sm;
                #pragma unroll 10
                for (int j = 0; j < 30; ++j) rowp[j] = __expf(rowp[j] - mx) * inv;
                if (part == 3) {
                    #pragma unroll
                    for (int c = 120; c < 128; ++c) Sf[rl*132 + c] = 0.f;
                }
            }
        }
        __syncthreads();
        floatx4 pacc[2];
        pacc[0] = (floatx4){0.f,0.f,0.f,0.f};
        pacc[1] = (floatx4){0.f,0.f,0.f,0.f};
        #pragma unroll
        for (int s = 0; s < 4; ++s) {
            const float* pr = &Sf[(wave*16 + ml)*132 + 32*s + 8*q];
            float4 p0 = *(const float4*)pr;
            float4 p1 = *(const float4*)(pr + 4);
            bf16x8 af2 = {(bf16)p0.x,(bf16)p0.y,(bf16)p0.z,(bf16)p0.w,
                          (bf16)p1.x,(bf16)p1.y,(bf16)p1.z,(bf16)p1.w};
            #pragma unroll
            for (int nv = 0; nv < 2; ++nv) {
                int e = nv*16 + ml;
                bf16x8 bfr = *(const bf16x8*)&VT[e*128 + ((((4*s+q) ^ (e & 15)))*8)];
                pacc[nv] = __builtin_amdgcn_mfma_f32_16x16x32_bf16(af2, bfr, pacc[nv], 0, 0, 0);
            }
        }
        #pragma unroll
        for (int nv = 0; nv < 2; ++nv)
            #pragma unroll
            for (int r = 0; r < 4; ++r) {
                int row = hf*64 + wave*16 + q*4 + r;
                if (row < TT)
                    O[((size_t)b*TT + row)*DD + hh*32 + nv*16 + ml] = (bf16)pacc[nv][r];
            }
        __syncthreads();
    }
}

// ---------------------------------------------------------------------------
// Pool+ctx+rv (proven).
__global__ __launch_bounds__(128) void pool_ctx3(
    const float* __restrict__ h, const float* __restrict__ x,
    const int* __restrict__ sym_id, const int* __restrict__ regime_id,
    const float* __restrict__ sym_emb, const float* __restrict__ reg_emb,
    const float* __restrict__ pool_w, const float* __restrict__ pool_b,
    const float* __restrict__ ctx_w, const float* __restrict__ ctx_b,
    float* __restrict__ ctxf, float* __restrict__ rv)
{
    __shared__ float sc[120];
    __shared__ float aw[120];
    __shared__ float cat[152];
    const int b = blockIdx.x;
    const int tid = threadIdx.x, lane = tid & 63, wave = tid >> 6;
    const float* hb = h + (size_t)b*TT*DD;
    for (int t = wave*60; t < wave*60 + 60; ++t) {
        const float2* hp = (const float2*)(hb + t*DD);
        float2 v = hp[lane];
        float s = v.x * pool_w[lane*2] + v.y * pool_w[lane*2 + 1];
        #pragma unroll
        for (int o = 1; o < 64; o <<= 1) s += __shfl_xor(s, o);
        if (lane == 0) sc[t] = s + pool_b[0];
    }
    __syncthreads();
    if (wave == 0) {
        float v0 = sc[lane];
        float v1 = (lane < 56) ? sc[lane + 64] : -3e38f;
        float mx = fmaxf(v0, v1);
        #pragma unroll
        for (int o = 1; o < 64; o <<= 1) mx = fmaxf(mx, __shfl_xor(mx, o));
        float e0 = expf(v0 - mx);
        float e1 = (lane < 56) ? expf(v1 - mx) : 0.f;
        float sm = e0 + e1;
        #pragma unroll
        for (int o = 1; o < 64; o <<= 1) sm += __shfl_xor(sm, o);
        float inv = 1.f / sm;
        aw[lane] = e0 * inv;
        if (lane < 56) aw[lane + 64] = e1 * inv;
    } else {
        float v0 = x[((size_t)b*TT + lane)*FF];
        float v1 = (lane < 56) ? x[((size_t)b*TT + lane + 64)*FF] : 0.f;
        float s = v0 + v1;
        #pragma unroll
        for (int o = 1; o < 64; o <<= 1) s += __shfl_xor(s, o);
        float mean = s / 120.f;
        float d0 = v0 - mean, d1 = (lane < 56) ? (v1 - mean) : 0.f;
        float ss = d0*d0 + d1*d1;
        #pragma unroll
        for (int o = 1; o < 64; o <<= 1) ss += __shfl_xor(ss, o);
        if (lane == 0) rv[b] = sqrtf(ss / 119.f);
    }
    __syncthreads();
    {
        float p = 0.f;
        for (int t = 0; t < TT; ++t) p += aw[t] * hb[(size_t)t*DD + tid];
        cat[tid] = p;
    }
    if (tid < 16)      cat[128 + tid] = sym_emb[(size_t)sym_id[b]*16 + tid];
    else if (tid < 24) cat[144 + (tid-16)] = reg_emb[regime_id[b]*8 + (tid-16)];
    __syncthreads();
    float acc = ctx_b[tid];
    const float* wr = ctx_w + (size_t)tid*152;
    for (int j = 0; j < 152; ++j) acc += cat[j] * wr[j];
    ctxf[(size_t)b*128 + tid] = acc;
}

// ---------------------------------------------------------------------------
// GRU v5 (proven R9, verbatim): 64 blocks x 16 rows x 512 threads.
#define G1IDX(rr,c) ((rr)*132 + (c) + ((c)>>5))
__global__ __launch_bounds__(512, 1) void gru5_kernel(
    const float* __restrict__ ctxf, const float* __restrict__ wih,
    const float* __restrict__ bih, const float* __restrict__ whh,
    const float* __restrict__ bhh,
    const float* __restrict__ mu_w1, const float* __restrict__ mu_b1,
    const float* __restrict__ mu_w2, const float* __restrict__ mu_b2,
    const float* __restrict__ vol_w1, const float* __restrict__ vol_b1,
    const float* __restrict__ vol_w2, const float* __restrict__ vol_b2,
    const float* __restrict__ rv, float* __restrict__ out)
{
    __shared__ alignas(16) bf16 hdh[2][16*128];
    __shared__ alignas(16) bf16 hdl[2][16*128];
    __shared__ float g1_s[16*132];
    __shared__ float step_s[80];
    __shared__ float w2m_s[320], w2v_s[320];
    __shared__ float rvv[16];
    const int tid = threadIdx.x, lane = tid & 63, wave = tid >> 6;  // 8 waves
    const int q = lane >> 4, ml = lane & 15;
    const int col = wave*16 + ml;
    const int r0 = blockIdx.x * 16;

    bf16x8 wbh1[3][4], wbl1[3][4], wbh2[4], wbl2[4];
    float w50[5], w51[5], w52[5];
    #pragma unroll
    for (int g = 0; g < 3; ++g) {
        int n = g*128 + col;
        #pragma unroll
        for (int s = 0; s < 4; ++s) {
            const float* wp = whh + (size_t)n*128 + s*32 + q*8;
            float4 f0 = *(const float4*)wp;
            float4 f1 = *(const float4*)(wp + 4);
            float v[8] = {f0.x,f0.y,f0.z,f0.w,f1.x,f1.y,f1.z,f1.w};
            bf16x8 hi, lo;
            #pragma unroll
            for (int j = 0; j < 8; ++j) {
                bf16 hb = (bf16)v[j]; hi[j] = hb; lo[j] = (bf16)(v[j] - (float)hb);
            }
            wbh1[g][s] = hi; wbl1[g][s] = lo;
        }
        #pragma unroll
        for (int j = 0; j < 5; ++j) {
            float wv = wih[(size_t)n*133 + j];
            if (g == 0) w50[j] = wv; else if (g == 1) w51[j] = wv; else w52[j] = wv;
        }
    }
    const float bhh0 = bhh[col], bhh1 = bhh[128 + col], bhh2 = bhh[256 + col];
    float bias2 = (col < 64) ? mu_b1[col] : vol_b1[col - 64];
    #pragma unroll
    for (int s = 0; s < 4; ++s) {
        const float* wp = ((col < 64) ? (mu_w1 + (size_t)col*128)
                                      : (vol_w1 + (size_t)(col-64)*128)) + s*32 + q*8;
        float4 f0 = *(const float4*)wp;
        float4 f1 = *(const float4*)(wp + 4);
        float v[8] = {f0.x,f0.y,f0.z,f0.w,f1.x,f1.y,f1.z,f1.w};
        bf16x8 hi, lo;
        #pragma unroll
        for (int j = 0; j < 8; ++j) {
            bf16 hb = (bf16)v[j]; hi[j] = hb; lo[j] = (bf16)(v[j] - (float)hb);
        }
        wbh2[s] = hi; wbl2[s] = lo;
    }

    for (int i = tid; i < 2048; i += 512) {
        int rr = i >> 7, d = i & 127;
        float v = ctxf[(size_t)r0*128 + i];
        g1_s[G1IDX(rr, d)] = v;
        int pos = rr*128 + (((d>>3) ^ rr) & 15)*8 + (d & 7);
        bf16 hb = (bf16)v;
        hdh[0][pos] = hb;
        hdl[0][pos] = (bf16)(v - (float)hb);
    }
    for (int i = tid; i < 320; i += 512) { w2m_s[i] = mu_w2[i]; w2v_s[i] = vol_w2[i]; }
    if (tid < 80) step_s[tid] = 0.f;
    if (tid < 16) rvv[tid] = 1.f + rv[r0 + tid];
    __syncthreads();
    float gi0[4], gi1[4], gi2[4];
    #pragma unroll
    for (int g = 0; g < 3; ++g) {
        int n = g*128 + col;
        const float* wr = wih + (size_t)n*133 + 5;
        #pragma unroll
        for (int r = 0; r < 4; ++r) {
            int row = q*4 + r;
            float a = bih[n];
            #pragma unroll 4
            for (int k = 0; k < 128; ++k) a += g1_s[G1IDX(row, k)] * wr[k];
            if (g == 0) gi0[r] = a; else if (g == 1) gi1[r] = a; else gi2[r] = a;
        }
    }
    __syncthreads();

    int cur = 0;
    for (int st = 0; st < HOR; ++st) {
        const int nxt = cur ^ 1;
        {
            bf16x8 ah[4], al[4];
            #pragma unroll
            for (int s = 0; s < 4; ++s) {
                int off = ml*128 + (((s*4 + q) ^ ml) & 15)*8;
                ah[s] = *(const bf16x8*)&hdh[cur][off];
                al[s] = *(const bf16x8*)&hdl[cur][off];
            }
            floatx4 a1 = (floatx4){0,0,0,0}, a2 = (floatx4){0,0,0,0}, a3 = (floatx4){0,0,0,0};
            floatx4 b1 = (floatx4){0,0,0,0}, b2 = (floatx4){0,0,0,0}, b3 = (floatx4){0,0,0,0};
            floatx4 c1 = (floatx4){0,0,0,0}, c2 = (floatx4){0,0,0,0}, c3 = (floatx4){0,0,0,0};
            #pragma unroll
            for (int s = 0; s < 4; ++s) {
                a1 = __builtin_amdgcn_mfma_f32_16x16x32_bf16(ah[s], wbh1[0][s], a1, 0, 0, 0);
                a2 = __builtin_amdgcn_mfma_f32_16x16x32_bf16(ah[s], wbl1[0][s], a2, 0, 0, 0);
                a3 = __builtin_amdgcn_mfma_f32_16x16x32_bf16(al[s], wbh1[0][s], a3, 0, 0, 0);
                b1 = __builtin_amdgcn_mfma_f32_16x16x32_bf16(ah[s], wbh1[1][s], b1, 0, 0, 0);
                b2 = __builtin_amdgcn_mfma_f32_16x16x32_bf16(ah[s], wbl1[1][s], b2, 0, 0, 0);
                b3 = __builtin_amdgcn_mfma_f32_16x16x32_bf16(al[s], wbh1[1][s], b3, 0, 0, 0);
                c1 = __builtin_amdgcn_mfma_f32_16x16x32_bf16(ah[s], wbh1[2][s], c1, 0, 0, 0);
                c2 = __builtin_amdgcn_mfma_f32_16x16x32_bf16(ah[s], wbl1[2][s], c2, 0, 0, 0);
                c3 = __builtin_amdgcn_mfma_f32_16x16x32_bf16(al[s], wbh1[2][s], c3, 0, 0, 0);
            }
            floatx4 ar = a1 + a2 + a3;
            floatx4 az = b1 + b2 + b3;
            floatx4 an = c1 + c2 + c3;
            #pragma unroll
            for (int r = 0; r < 4; ++r) {
                int row = q*4 + r;
                float ir = gi0[r], iz = gi1[r], in_ = gi2[r];
                #pragma unroll
                for (int j = 0; j < 5; ++j) {
                    float sv = step_s[row*5 + j];
                    ir  += sv * w50[j];
                    iz  += sv * w51[j];
                    in_ += sv * w52[j];
                }
                float rg = fast_sigmoid(ir + ar[r] + bhh0);
                float zg = fast_sigmoid(iz + az[r] + bhh1);
                float nn = fast_tanh(in_ + rg*(an[r] + bhh2));
                int pos = row*128 + (((col>>3) ^ row) & 15)*8 + (col & 7);
                float hold = (float)hdh[cur][pos] + (float)hdl[cur][pos];
                float hnew = (1.f - zg)*nn + zg*hold;
                bf16 hb = (bf16)hnew;
                hdh[nxt][pos] = hb;
                hdl[nxt][pos] = (bf16)(hnew - (float)hb);
            }
        }
        __syncthreads();
        {
            bf16x8 ah[4], al[4];
            #pragma unroll
            for (int s = 0; s < 4; ++s) {
                int off = ml*128 + (((s*4 + q) ^ ml) & 15)*8;
                ah[s] = *(const bf16x8*)&hdh[nxt][off];
                al[s] = *(const bf16x8*)&hdl[nxt][off];
            }
            floatx4 d1 = (floatx4){0,0,0,0}, d2 = (floatx4){0,0,0,0}, d3 = (floatx4){0,0,0,0};
            #pragma unroll
            for (int s = 0; s < 4; ++s) {
                d1 = __builtin_amdgcn_mfma_f32_16x16x32_bf16(ah[s], wbh2[s], d1, 0, 0, 0);
                d2 = __builtin_amdgcn_mfma_f32_16x16x32_bf16(ah[s], wbl2[s], d2, 0, 0, 0);
                d3 = __builtin_amdgcn_mfma_f32_16x16x32_bf16(al[s], wbh2[s], d3, 0, 0, 0);
            }
            floatx4 a4 = d1 + d2 + d3;
            #pragma unroll
            for (int r = 0; r < 4; ++r) {
                float u = a4[r] + bias2;
                g1_s[G1IDX(q*4 + r, col)] = 0.5f*u*(1.f + erff(u*0.70710678118654752f));
            }
        }
        __syncthreads();
        if (tid < 320) {
            int g = tid >> 2;
            int sub = tid & 3;
            int head = sub >> 1, half = sub & 1;
            int rr = g / 5, o = g % 5;
            const float* w2 = head ? w2v_s : w2m_s;
            int wb = o*64 + half*32;
            int gb = head*64 + half*32;
            float s = 0.f;
            #pragma unroll 8
            for (int j = 0; j < 32; ++j)
                s += g1_s[G1IDX(rr, gb + j)] * w2[wb + j];
            s += __shfl_xor(s, 1);
            float resv;
            if (head == 0) resv = tanhf(s + mu_b2[o]);
            else {
                float av = s + vol_b2[o];
                float sp = (av > 20.f) ? av : log1pf(expf(av));
                resv = sp * rvv[rr];
            }
            float other = __shfl_xor(resv, 2);
            if (sub == 0) {
                float pr = resv * other;
                step_s[g] = pr;
                out[((size_t)(r0 + rr)*HOR + st)*MM + o] = pr;
            }
        }
        __syncthreads();
        cur = nxt;
    }
}

// ---------------------------------------------------------------------------
extern "C" void kernel_launch(void* const* d_in, const int* in_sizes, int n_in,
                              void* d_out, int out_size, void* d_ws, size_t ws_size,
                              hipStream_t stream)
{
    (void)in_sizes; (void)n_in; (void)out_size;
    const float* x        = (const float*)d_in[0];
    const int*   sym_id   = (const int*)d_in[1];
    const int*   regime_id= (const int*)d_in[2];
    const float* sym_emb  = (const float*)d_in[3];
    const float* reg_emb  = (const float*)d_in[4];
    const float* in_w     = (const float*)d_in[5];
    const float* in_b     = (const float*)d_in[6];
    const float* qkv_w    = (const float*)d_in[7];
    const float* qkv_b    = (const float*)d_in[8];
    const float* out_w    = (const float*)d_in[9];
    const float* out_bv   = (const float*)d_in[10];
    const float* ln1_w    = (const float*)d_in[11];
    const float* ln1_b    = (const float*)d_in[12];
    const float* ln2_w    = (const float*)d_in[13];
    const float* ln2_b    = (const float*)d_in[14];
    const float* f1_w     = (const float*)d_in[15];
    const float* f1_b     = (const float*)d_in[16];
    const float* f2_w     = (const float*)d_in[17];
    const float* f2_b     = (const float*)d_in[18];
    const float* pool_w   = (const float*)d_in[19];
    const float* pool_b   = (const float*)d_in[20];
    const float* ctx_w    = (const float*)d_in[21];
    const float* ctx_b    = (const float*)d_in[22];
    const float* gru_wih  = (const float*)d_in[23];
    const float* gru_whh  = (const float*)d_in[24];
    const float* gru_bih  = (const float*)d_in[25];
    const float* gru_bhh  = (const float*)d_in[26];
    const float* mu_w1    = (const float*)d_in[27];
    const float* mu_b1    = (const float*)d_in[28];
    const float* mu_w2    = (const float*)d_in[29];
    const float* mu_b2    = (const float*)d_in[30];
    const float* vol_w1   = (const float*)d_in[31];
    const float* vol_b1   = (const float*)d_in[32];
    const float* vol_w2   = (const float*)d_in[33];
    const float* vol_b2   = (const float*)d_in[34];
    float* outp = (float*)d_out;

    char* ws = (char*)d_ws;
    size_t off = 0;
    auto alloc = [&](size_t bytes) -> void* {
        void* p = ws + off;
        off = (off + bytes + 255) & ~(size_t)255;
        return p;
    };
    float* h    = (float*)alloc((size_t)NROWS*DD*4);
    bf16*  y    = (bf16*) alloc((size_t)NROWS*DD*2);
    bf16*  wbf  = (bf16*) alloc((size_t)393216*2);
    float* ctxf = (float*)alloc((size_t)BB*DD*4);
    float* rv   = (float*)alloc((size_t)BB*4);
    // big holds qkv only now (ffn is fused): 94.4MB full, chunkable
    size_t avail = (ws_size > off) ? (ws_size - off) : 0;
    int nch;
    if      (avail >= (size_t)NROWS*384*2)     nch = 1;
    else if (avail >= (size_t)NROWS/2*384*2)   nch = 2;
    else                                       nch = 4;
    const int RC = NROWS / nch;
    const int BC = BB / nch;
    bf16* big = (bf16*)(ws + off);

    prep_weights<<<1536, 256, 0, stream>>>(qkv_w, out_w, f1_w, f2_w, wbf);
    inproj3<<<NROWS/4, 256, 0, stream>>>(x, sym_id, sym_emb, in_w, in_b,
                                         ln1_w, ln1_b, h, y);

    for (int l = 0; l < 2; ++l) {
        const bf16* wqkv = wbf + l*49152;
        const bf16* wout = wbf + 98304 + l*16384;
        const bf16* wf1  = wbf + 131072 + l*65536;
        const bf16* wf2  = wbf + 262144 + l*65536;
        for (int c = 0; c < nch; ++c) {
            const size_t ro = (size_t)c*RC;
            gemm64<0><<<dim3(RC/128, 3), 256, 0, stream>>>(
                y + ro*DD, wqkv, qkv_b + l*384, nullptr, big,
                nullptr, nullptr, nullptr, 384, 128);
            attn_b16<<<BC*4, 256, 0, stream>>>(big, y + ro*DD);
        }
        gemm64<3><<<dim3(NROWS/128, 1), 256, 0, stream>>>(
            y, wout, out_bv + l*128, h, h, ln2_w + l*128, ln2_b + l*128, y, 128, 128);
        if (l == 0)
            ffn_fused<1><<<NROWS/64, 256, 0, stream>>>(
                y, wf1, f1_b, wf2, f2_b, h, ln1_w + 128, ln1_b + 128, y);
        else
            ffn_fused<0><<<NROWS/64, 256, 0, stream>>>(
                y, wf1, f1_b + 512, wf2, f2_b + 128, h, nullptr, nullptr, y);
    }

    pool_ctx3<<<BB, 128, 0, stream>>>(h, x, sym_id, regime_id, sym_emb, reg_emb,
                                      pool_w, pool_b, ctx_w, ctx_b, ctxf, rv);
    gru5_kernel<<<64, 512, 0, stream>>>(ctxf, gru_wih, gru_bih, gru_whh, gru_bhh,
                                        mu_w1, mu_b1, mu_w2, mu_b2,
                                        vol_w1, vol_b1, vol_w2, vol_b2,
                                        rv, outp);
}

// Round 12
// 1357.227 us; speedup vs baseline: 1.3612x; 1.0987x over previous
//
#include <hip/hip_runtime.h>
#include <math.h>

typedef __bf16 bf16;
typedef __bf16 bf16x8 __attribute__((ext_vector_type(8)));
typedef __bf16 bf16x2 __attribute__((ext_vector_type(2)));
typedef float  floatx4 __attribute__((ext_vector_type(4)));

// dims
#define BB 1024
#define TT 120
#define FF 32
#define DD 128
#define NROWS (BB*TT)      // 122880
#define HOR 90
#define MM 5

__device__ __forceinline__ float fast_sigmoid(float x) {
    x = fminf(fmaxf(x, -30.f), 30.f);
    return 1.f / (1.f + __expf(-x));
}
__device__ __forceinline__ float fast_tanh(float x) {
    x = fminf(fmaxf(x, -15.f), 15.f);
    float e = __expf(-2.f * x);
    return (1.f - e) / (1.f + e);
}

// ---------------------------------------------------------------------------
// Encoder weights -> bf16.
__global__ __launch_bounds__(256) void prep_weights(
    const float* __restrict__ qkv, const float* __restrict__ outw,
    const float* __restrict__ f1,  const float* __restrict__ f2,
    bf16* __restrict__ dst)
{
    int i = blockIdx.x*256 + threadIdx.x;
    if (i >= 393216) return;
    float v;
    if      (i < 98304)  v = qkv[i];
    else if (i < 131072) v = outw[i - 98304];
    else if (i < 262144) v = f1[i - 131072];
    else                 v = f2[i - 262144];
    dst[i] = (bf16)v;
}

// ---------------------------------------------------------------------------
// Input projection + PE + fused ln1(L0). 4 rows/block, one wave per row.
__global__ __launch_bounds__(256) void inproj3(
    const float* __restrict__ x, const int* __restrict__ sym_id,
    const float* __restrict__ sym_emb, const float* __restrict__ in_w,
    const float* __restrict__ in_b, const float* __restrict__ lnw,
    const float* __restrict__ lnb, float* __restrict__ h, bf16* __restrict__ y)
{
    __shared__ float xin[4][48];
    const int tid = threadIdx.x, lane = tid & 63, wave = tid >> 6;
    const int row0 = blockIdx.x * 4;
    if (tid < 192) {
        int rr = tid / 48, k = tid % 48;
        int row = row0 + rr;
        int b = row / TT;
        xin[rr][k] = (k < 32) ? x[(size_t)row*FF + k]
                              : sym_emb[(size_t)sym_id[b]*16 + (k - 32)];
    }
    __syncthreads();
    const int row = row0 + wave;
    const int t = row % TT;
    const int d0 = lane*2;
    float a0 = in_b[d0], a1 = in_b[d0+1];
    const float* w0 = in_w + (size_t)d0*48;
    const float* w1 = w0 + 48;
    #pragma unroll 8
    for (int k = 0; k < 48; ++k) {
        float xv = xin[wave][k];
        a0 += xv * w0[k];
        a1 += xv * w1[k];
    }
    const float f = expf((float)d0 * (-9.210340371976184f / 128.f));
    const float arg = (float)t * f;
    a0 += sinf(arg);
    a1 += cosf(arg);
    float2 hv = {a0, a1};
    *(float2*)&h[(size_t)row*DD + d0] = hv;
    float s = a0 + a1, ss = a0*a0 + a1*a1;
    #pragma unroll
    for (int o = 1; o < 64; o <<= 1) { s += __shfl_xor(s, o); ss += __shfl_xor(ss, o); }
    float mean = s * (1.f/128.f);
    float var  = ss * (1.f/128.f) - mean*mean;
    float rstd = rsqrtf(var + 1e-5f);
    bf16x2 o2 = {(bf16)((a0 - mean)*rstd*lnw[d0]   + lnb[d0]),
                 (bf16)((a1 - mean)*rstd*lnw[d0+1] + lnb[d0+1])};
    *(bf16x2*)&y[(size_t)row*DD + d0] = o2;
}

// ---------------------------------------------------------------------------
// bf16 MFMA GEMM, BK=64 (proven R10). EPI: 0 bias->bf16, 1 bias+relu->bf16,
// 2 bias+res->f32, 3 bias+res->f32 AND fused row-LN->bf16 (N==128).
template<int EPI>
__global__ __launch_bounds__(256) void gemm64(
    const bf16* __restrict__ A, const bf16* __restrict__ W,
    const float* __restrict__ bias, const float* __restrict__ res,
    void* __restrict__ outp, const float* __restrict__ lnw,
    const float* __restrict__ lnb, bf16* __restrict__ yout, int N, int K)
{
    __shared__ alignas(16) bf16 As[128*64];
    __shared__ alignas(16) bf16 Ws[128*64];
    __shared__ float psum[2][128];
    __shared__ float psq[2][128];
    const int tid = threadIdx.x;
    const int lane = tid & 63, wave = tid >> 6;
    const int q = lane >> 4, ml = lane & 15;
    const int wm = (wave & 1) * 64, wn = (wave >> 1) * 64;
    const int m0 = blockIdx.x * 128, n0 = blockIdx.y * 128;
    floatx4 acc[4][4];
    #pragma unroll
    for (int i = 0; i < 4; ++i)
        #pragma unroll
        for (int j = 0; j < 4; ++j) acc[i][j] = (floatx4){0.f,0.f,0.f,0.f};
    const int nkb = K >> 6;
    for (int kb = 0; kb < nkb; ++kb) {
        #pragma unroll
        for (int i = 0; i < 4; ++i) {
            int idx = i*256 + tid;
            int r = idx >> 3, c = idx & 7;
            int sw = ((c ^ (r & 7)) * 8);
            *(uint4*)&As[r*64 + sw] = *(const uint4*)(A + (size_t)(m0 + r)*K + kb*64 + c*8);
            *(uint4*)&Ws[r*64 + sw] = *(const uint4*)(W + (size_t)(n0 + r)*K + kb*64 + c*8);
        }
        __syncthreads();
        #pragma unroll
        for (int s = 0; s < 2; ++s) {
            bf16x8 af[4], bfr[4];
            #pragma unroll
            for (int t = 0; t < 4; ++t) {
                int ra = wm + t*16 + ml;
                af[t]  = *(const bf16x8*)&As[ra*64 + (((s*4+q) ^ (ra & 7))*8)];
                int rb = wn + t*16 + ml;
                bfr[t] = *(const bf16x8*)&Ws[rb*64 + (((s*4+q) ^ (rb & 7))*8)];
            }
            #pragma unroll
            for (int i = 0; i < 4; ++i)
                #pragma unroll
                for (int j = 0; j < 4; ++j)
                    acc[i][j] = __builtin_amdgcn_mfma_f32_16x16x32_bf16(af[i], bfr[j], acc[i][j], 0, 0, 0);
        }
        __syncthreads();
    }
    #pragma unroll
    for (int j = 0; j < 4; ++j) {
        int col = n0 + wn + j*16 + ml;
        float bv = bias[col];
        #pragma unroll
        for (int i = 0; i < 4; ++i) {
            #pragma unroll
            for (int r = 0; r < 4; ++r) {
                int row = m0 + wm + i*16 + q*4 + r;
                size_t o = (size_t)row * N + col;
                float v = acc[i][j][r] + bv;
                if      (EPI == 0) ((bf16*)outp)[o] = (bf16)v;
                else if (EPI == 1) ((bf16*)outp)[o] = (bf16)fmaxf(v, 0.f);
                else {
                    v += res[o];
                    ((float*)outp)[o] = v;
                    acc[i][j][r] = v;
                }
            }
        }
    }
    if (EPI == 3) {
        float lw[4], lb[4];
        #pragma unroll
        for (int j = 0; j < 4; ++j) { int col = wn + j*16 + ml; lw[j] = lnw[col]; lb[j] = lnb[col]; }
        #pragma unroll
        for (int i = 0; i < 4; ++i)
            #pragma unroll
            for (int r = 0; r < 4; ++r) {
                float s  = acc[i][0][r] + acc[i][1][r] + acc[i][2][r] + acc[i][3][r];
                float ss = acc[i][0][r]*acc[i][0][r] + acc[i][1][r]*acc[i][1][r]
                         + acc[i][2][r]*acc[i][2][r] + acc[i][3][r]*acc[i][3][r];
                #pragma unroll
                for (int o = 1; o < 16; o <<= 1) { s += __shfl_xor(s, o); ss += __shfl_xor(ss, o); }
                if (ml == 0) {
                    int row = wm + i*16 + q*4 + r;
                    psum[wn >> 6][row] = s;
                    psq [wn >> 6][row] = ss;
                }
            }
        __syncthreads();
        #pragma unroll
        for (int i = 0; i < 4; ++i)
            #pragma unroll
            for (int r = 0; r < 4; ++r) {
                int row = wm + i*16 + q*4 + r;
                float mean = (psum[0][row] + psum[1][row]) * (1.f/128.f);
                float var  = (psq[0][row] + psq[1][row]) * (1.f/128.f) - mean*mean;
                float rstd = rsqrtf(var + 1e-5f);
                #pragma unroll
                for (int j = 0; j < 4; ++j) {
                    int col = wn + j*16 + ml;
                    yout[(size_t)(m0 + row)*128 + col] =
                        (bf16)((acc[i][j][r] - mean)*rstd*lw[j] + lb[j]);
                }
            }
    }
}

// ---------------------------------------------------------------------------
// Fused FFN v2: interleaved ffn1/ffn2 halves, 80KB LDS -> 2 blocks/CU.
// h += W2 @ relu(W1 @ y + b1) + b2 per 64-row tile.
// LNFUSE=1: also emit y = rowLN(h).
template<int LNFUSE>
__global__ __launch_bounds__(256) void ffn_fused(
    const bf16* __restrict__ y, const bf16* __restrict__ W1,
    const float* __restrict__ b1, const bf16* __restrict__ W2,
    const float* __restrict__ b2, float* __restrict__ h,
    const float* __restrict__ lnw, const float* __restrict__ lnb,
    bf16* __restrict__ yout)
{
    __shared__ alignas(16) bf16 ys[64*128];      // 16KB
    __shared__ alignas(16) bf16 mid[2][64*128];  // 32KB
    __shared__ alignas(16) bf16 wbuf[128*128];   // 32KB -> 80KB total
    const int tid = threadIdx.x;
    const int lane = tid & 63, wave = tid >> 6;   // 4 waves
    const int q = lane >> 4, ml = lane & 15;
    const int wm = wave * 16;                     // 16 rows per wave
    const int m0 = blockIdx.x * 64;
    // stage y rows (64 x 128), swizzled like gemm As
    #pragma unroll
    for (int i = 0; i < 4; ++i) {
        int idx = i*256 + tid;
        int r = idx >> 4, cc = idx & 15;
        *(uint4*)&ys[r*128 + ((cc ^ (r & 15))*8)] =
            *(const uint4*)(y + (size_t)(m0 + r)*128 + cc*8);
    }
    floatx4 acc2[8];
    #pragma unroll
    for (int j = 0; j < 8; ++j) acc2[j] = (floatx4){0.f,0.f,0.f,0.f};
    for (int half = 0; half < 2; ++half) {
        // ---- phase 1: mid[j2] = relu(ys @ W1_nb^T + b1), nb = half*2+j2
        for (int j2 = 0; j2 < 2; ++j2) {
            int nb = half*2 + j2;
            __syncthreads();                      // wbuf free (ys ready 1st iter)
            #pragma unroll
            for (int i = 0; i < 8; ++i) {
                int idx = i*256 + tid;
                int r = idx >> 4, cc = idx & 15;
                *(uint4*)&wbuf[r*128 + ((cc ^ (r & 15))*8)] =
                    *(const uint4*)(W1 + (size_t)(nb*128 + r)*128 + cc*8);
            }
            __syncthreads();
            bf16x8 af[4];
            #pragma unroll
            for (int s = 0; s < 4; ++s) {
                int ra = wm + ml;
                af[s] = *(const bf16x8*)&ys[ra*128 + (((4*s+q) ^ (ra & 15))*8)];
            }
            #pragma unroll
            for (int j = 0; j < 8; ++j) {
                floatx4 acc = (floatx4){0.f,0.f,0.f,0.f};
                #pragma unroll
                for (int s = 0; s < 4; ++s) {
                    int rb = j*16 + ml;
                    bf16x8 bfr = *(const bf16x8*)&wbuf[rb*128 + (((4*s+q) ^ (rb & 15))*8)];
                    acc = __builtin_amdgcn_mfma_f32_16x16x32_bf16(af[s], bfr, acc, 0, 0, 0);
                }
                int col = j*16 + ml;
                float bv = b1[nb*128 + col];
                #pragma unroll
                for (int r = 0; r < 4; ++r) {
                    int row = wm + q*4 + r;
                    float v = fmaxf(acc[r] + bv, 0.f);
                    mid[j2][row*128 + (((col>>3) ^ (row & 15))*8) + (col & 7)] = (bf16)v;
                }
            }
        }
        // ---- phase 2: acc2 += mid[j2] @ W2_kb^T, kb = half*2+j2
        for (int j2 = 0; j2 < 2; ++j2) {
            int kb = half*2 + j2;
            __syncthreads();                      // mid[j2] ready, wbuf free
            #pragma unroll
            for (int i = 0; i < 8; ++i) {
                int idx = i*256 + tid;
                int r = idx >> 4, cc = idx & 15;
                *(uint4*)&wbuf[r*128 + ((cc ^ (r & 15))*8)] =
                    *(const uint4*)(W2 + (size_t)r*512 + kb*128 + cc*8);
            }
            __syncthreads();
            bf16x8 af[4];
            #pragma unroll
            for (int s = 0; s < 4; ++s) {
                int ra = wm + ml;
                af[s] = *(const bf16x8*)&mid[j2][ra*128 + (((4*s+q) ^ (ra & 15))*8)];
            }
            #pragma unroll
            for (int j = 0; j < 8; ++j) {
                #pragma unroll
                for (int s = 0; s < 4; ++s) {
                    int rb = j*16 + ml;
                    bf16x8 bfr = *(const bf16x8*)&wbuf[rb*128 + (((4*s+q) ^ (rb & 15))*8)];
                    acc2[j] = __builtin_amdgcn_mfma_f32_16x16x32_bf16(af[s], bfr, acc2[j], 0, 0, 0);
                }
            }
        }
    }
    // ---- epilogue: residual, h write, optional fused LN -> yout
    float vr[8][4];
    #pragma unroll
    for (int j = 0; j < 8; ++j) {
        int col = j*16 + ml;
        float bv = b2[col];
        #pragma unroll
        for (int r = 0; r < 4; ++r) {
            int row = wm + q*4 + r;
            size_t o = (size_t)(m0 + row)*128 + col;
            float v = acc2[j][r] + bv + h[o];
            h[o] = v;
            vr[j][r] = v;
        }
    }
    if (LNFUSE) {
        float lw[8], lb[8];
        #pragma unroll
        for (int j = 0; j < 8; ++j) { lw[j] = lnw[j*16 + ml]; lb[j] = lnb[j*16 + ml]; }
        #pragma unroll
        for (int r = 0; r < 4; ++r) {
            float s = 0.f, ss = 0.f;
            #pragma unroll
            for (int j = 0; j < 8; ++j) { s += vr[j][r]; ss += vr[j][r]*vr[j][r]; }
            #pragma unroll
            for (int o = 1; o < 16; o <<= 1) { s += __shfl_xor(s, o); ss += __shfl_xor(ss, o); }
            float mean = s * (1.f/128.f);
            float var  = ss * (1.f/128.f) - mean*mean;
            float rstd = rsqrtf(var + 1e-5f);
            int row = wm + q*4 + r;
            #pragma unroll
            for (int j = 0; j < 8; ++j)
                yout[(size_t)(m0 + row)*128 + j*16 + ml] =
                    (bf16)((vr[j][r] - mean)*rstd*lw[j] + lb[j]);
        }
    }
}

// ---------------------------------------------------------------------------
// bf16 MFMA attention v2: Q frags direct from global (no Qs), vectorized V
// staging. 49.8KB LDS -> 3 blocks/CU. One block per (b,h).
__global__ __launch_bounds__(256) void attn_b16(
    const bf16* __restrict__ qkv, bf16* __restrict__ O)
{
    __shared__ alignas(16) bf16 Ks[128*32];
    __shared__ alignas(16) bf16 VT[32*128];
    __shared__ float Sf[64*132];
    const int tid = threadIdx.x, lane = tid & 63, wave = tid >> 6;
    const int q = lane >> 4, ml = lane & 15;
    const int b = blockIdx.x >> 2, hh = blockIdx.x & 3;
    const bf16* base = qkv + (size_t)b*TT*384 + hh*32;
    // K staging (vectorized, pad rows zeroed)
    #pragma unroll
    for (int i = 0; i < 2; ++i) {
        int idx = i*256 + tid;
        int r = idx >> 2, cc = idx & 3;
        uint4 vk = {0,0,0,0};
        if (r < TT) vk = *(const uint4*)(base + (size_t)r*384 + 128 + cc*8);
        int cs = cc ^ ((r >> 1) & 3);
        *(uint4*)&Ks[r*32 + cs*8] = vk;
    }
    // VT zero-fill for pad t rows 120..127
    {
        int e = tid >> 3, t = 120 + (tid & 7);
        VT[e*128 + (((t >> 3) ^ (e & 15))*8) + (t & 7)] = (bf16)0.f;
    }
    // V staging: vector loads + LDS transpose stores
    #pragma unroll
    for (int i = 0; i < 2; ++i) {
        int idx = i*256 + tid;             // < 480 valid
        if (idx < 480) {
            int t = idx >> 2, c = idx & 3;
            uint4 vv = *(const uint4*)(base + (size_t)t*384 + 256 + c*8);
            bf16 tmp[8];
            *(uint4*)tmp = vv;
            #pragma unroll
            for (int jj = 0; jj < 8; ++jj) {
                int e = c*8 + jj;
                VT[e*128 + (((t >> 3) ^ (e & 15))*8) + (t & 7)] = tmp[jj];
            }
        }
    }
    __syncthreads();
    const float scale = 0.17677669529663687f;
    for (int hf = 0; hf < 2; ++hf) {
        // S = Q K^T * scale (Q frag direct from global)
        {
            int rowa = hf*64 + wave*16 + ml;
            bf16x8 af;
            #pragma unroll
            for (int j = 0; j < 8; ++j) af[j] = (bf16)0.f;
            if (rowa < TT) af = *(const bf16x8*)(base + (size_t)rowa*384 + q*8);
            #pragma unroll
            for (int ni = 0; ni < 8; ++ni) {
                int rowb = ni*16 + ml;
                bf16x8 bfr = *(const bf16x8*)&Ks[rowb*32 + ((q ^ ((rowb>>1)&3))*8)];
                floatx4 a4 = __builtin_amdgcn_mfma_f32_16x16x32_bf16(
                    af, bfr, (floatx4){0.f,0.f,0.f,0.f}, 0, 0, 0);
                #pragma unroll
                for (int r = 0; r < 4; ++r)
                    Sf[(wave*16 + q*4 + r)*132 + ni*16 + ml] = a4[r]*scale;
            }
        }
        __syncthreads();
        // softmax: 4 lanes/row, 30 cols each; pad cols zeroed
        {
            int rl = wave*16 + (lane >> 2);
            int part = lane & 3;
            int rg = hf*64 + rl;
            if (rg < TT) {
                float* rowp = &Sf[rl*132 + part*30];
                float mx = -3e38f;
                #pragma unroll 10
                for (int j = 0; j < 30; ++j) mx = fmaxf(mx, rowp[j]);
                mx = fmaxf(mx, __shfl_xor(mx, 1));
                mx = fmaxf(mx, __shfl_xor(mx, 2));
                float sm = 0.f;
                #pragma unroll 10
                for (int j = 0; j < 30; ++j) sm += __expf(rowp[j] - mx);
                sm += __shfl_xor(sm, 1);
                sm += __shfl_xor(sm, 2);
                float inv = 1.f / sm;
                #pragma unroll 10
                for (int j = 0; j < 30; ++j) rowp[j] = __expf(rowp[j] - mx) * inv;
                if (part == 3) {
                    #pragma unroll
                    for (int c = 120; c < 128; ++c) Sf[rl*132 + c] = 0.f;
                }
            }
        }
        __syncthreads();
        floatx4 pacc[2];
        pacc[0] = (floatx4){0.f,0.f,0.f,0.f};
        pacc[1] = (floatx4){0.f,0.f,0.f,0.f};
        #pragma unroll
        for (int s = 0; s < 4; ++s) {
            const float* pr = &Sf[(wave*16 + ml)*132 + 32*s + 8*q];
            float4 p0 = *(const float4*)pr;
            float4 p1 = *(const float4*)(pr + 4);
            bf16x8 af2 = {(bf16)p0.x,(bf16)p0.y,(bf16)p0.z,(bf16)p0.w,
                          (bf16)p1.x,(bf16)p1.y,(bf16)p1.z,(bf16)p1.w};
            #pragma unroll
            for (int nv = 0; nv < 2; ++nv) {
                int e = nv*16 + ml;
                bf16x8 bfr = *(const bf16x8*)&VT[e*128 + ((((4*s+q) ^ (e & 15)))*8)];
                pacc[nv] = __builtin_amdgcn_mfma_f32_16x16x32_bf16(af2, bfr, pacc[nv], 0, 0, 0);
            }
        }
        #pragma unroll
        for (int nv = 0; nv < 2; ++nv)
            #pragma unroll
            for (int r = 0; r < 4; ++r) {
                int row = hf*64 + wave*16 + q*4 + r;
                if (row < TT)
                    O[((size_t)b*TT + row)*DD + hh*32 + nv*16 + ml] = (bf16)pacc[nv][r];
            }
        __syncthreads();
    }
}

// ---------------------------------------------------------------------------
// Pool+ctx+rv (proven).
__global__ __launch_bounds__(128) void pool_ctx3(
    const float* __restrict__ h, const float* __restrict__ x,
    const int* __restrict__ sym_id, const int* __restrict__ regime_id,
    const float* __restrict__ sym_emb, const float* __restrict__ reg_emb,
    const float* __restrict__ pool_w, const float* __restrict__ pool_b,
    const float* __restrict__ ctx_w, const float* __restrict__ ctx_b,
    float* __restrict__ ctxf, float* __restrict__ rv)
{
    __shared__ float sc[120];
    __shared__ float aw[120];
    __shared__ float cat[152];
    const int b = blockIdx.x;
    const int tid = threadIdx.x, lane = tid & 63, wave = tid >> 6;
    const float* hb = h + (size_t)b*TT*DD;
    for (int t = wave*60; t < wave*60 + 60; ++t) {
        const float2* hp = (const float2*)(hb + t*DD);
        float2 v = hp[lane];
        float s = v.x * pool_w[lane*2] + v.y * pool_w[lane*2 + 1];
        #pragma unroll
        for (int o = 1; o < 64; o <<= 1) s += __shfl_xor(s, o);
        if (lane == 0) sc[t] = s + pool_b[0];
    }
    __syncthreads();
    if (wave == 0) {
        float v0 = sc[lane];
        float v1 = (lane < 56) ? sc[lane + 64] : -3e38f;
        float mx = fmaxf(v0, v1);
        #pragma unroll
        for (int o = 1; o < 64; o <<= 1) mx = fmaxf(mx, __shfl_xor(mx, o));
        float e0 = expf(v0 - mx);
        float e1 = (lane < 56) ? expf(v1 - mx) : 0.f;
        float sm = e0 + e1;
        #pragma unroll
        for (int o = 1; o < 64; o <<= 1) sm += __shfl_xor(sm, o);
        float inv = 1.f / sm;
        aw[lane] = e0 * inv;
        if (lane < 56) aw[lane + 64] = e1 * inv;
    } else {
        float v0 = x[((size_t)b*TT + lane)*FF];
        float v1 = (lane < 56) ? x[((size_t)b*TT + lane + 64)*FF] : 0.f;
        float s = v0 + v1;
        #pragma unroll
        for (int o = 1; o < 64; o <<= 1) s += __shfl_xor(s, o);
        float mean = s / 120.f;
        float d0 = v0 - mean, d1 = (lane < 56) ? (v1 - mean) : 0.f;
        float ss = d0*d0 + d1*d1;
        #pragma unroll
        for (int o = 1; o < 64; o <<= 1) ss += __shfl_xor(ss, o);
        if (lane == 0) rv[b] = sqrtf(ss / 119.f);
    }
    __syncthreads();
    {
        float p = 0.f;
        for (int t = 0; t < TT; ++t) p += aw[t] * hb[(size_t)t*DD + tid];
        cat[tid] = p;
    }
    if (tid < 16)      cat[128 + tid] = sym_emb[(size_t)sym_id[b]*16 + tid];
    else if (tid < 24) cat[144 + (tid-16)] = reg_emb[regime_id[b]*8 + (tid-16)];
    __syncthreads();
    float acc = ctx_b[tid];
    const float* wr = ctx_w + (size_t)tid*152;
    for (int j = 0; j < 152; ++j) acc += cat[j] * wr[j];
    ctxf[(size_t)b*128 + tid] = acc;
}

// ---------------------------------------------------------------------------
// GRU v5 (proven R9/R11) with fast transcendentals in phase 3.
#define G1IDX(rr,c) ((rr)*132 + (c) + ((c)>>5))
__global__ __launch_bounds__(512, 1) void gru5_kernel(
    const float* __restrict__ ctxf, const float* __restrict__ wih,
    const float* __restrict__ bih, const float* __restrict__ whh,
    const float* __restrict__ bhh,
    const float* __restrict__ mu_w1, const float* __restrict__ mu_b1,
    const float* __restrict__ mu_w2, const float* __restrict__ mu_b2,
    const float* __restrict__ vol_w1, const float* __restrict__ vol_b1,
    const float* __restrict__ vol_w2, const float* __restrict__ vol_b2,
    const float* __restrict__ rv, float* __restrict__ out)
{
    __shared__ alignas(16) bf16 hdh[2][16*128];
    __shared__ alignas(16) bf16 hdl[2][16*128];
    __shared__ float g1_s[16*132];
    __shared__ float step_s[80];
    __shared__ float w2m_s[320], w2v_s[320];
    __shared__ float rvv[16];
    const int tid = threadIdx.x, lane = tid & 63, wave = tid >> 6;  // 8 waves
    const int q = lane >> 4, ml = lane & 15;
    const int col = wave*16 + ml;
    const int r0 = blockIdx.x * 16;

    bf16x8 wbh1[3][4], wbl1[3][4], wbh2[4], wbl2[4];
    float w50[5], w51[5], w52[5];
    #pragma unroll
    for (int g = 0; g < 3; ++g) {
        int n = g*128 + col;
        #pragma unroll
        for (int s = 0; s < 4; ++s) {
            const float* wp = whh + (size_t)n*128 + s*32 + q*8;
            float4 f0 = *(const float4*)wp;
            float4 f1 = *(const float4*)(wp + 4);
            float v[8] = {f0.x,f0.y,f0.z,f0.w,f1.x,f1.y,f1.z,f1.w};
            bf16x8 hi, lo;
            #pragma unroll
            for (int j = 0; j < 8; ++j) {
                bf16 hb = (bf16)v[j]; hi[j] = hb; lo[j] = (bf16)(v[j] - (float)hb);
            }
            wbh1[g][s] = hi; wbl1[g][s] = lo;
        }
        #pragma unroll
        for (int j = 0; j < 5; ++j) {
            float wv = wih[(size_t)n*133 + j];
            if (g == 0) w50[j] = wv; else if (g == 1) w51[j] = wv; else w52[j] = wv;
        }
    }
    const float bhh0 = bhh[col], bhh1 = bhh[128 + col], bhh2 = bhh[256 + col];
    float bias2 = (col < 64) ? mu_b1[col] : vol_b1[col - 64];
    #pragma unroll
    for (int s = 0; s < 4; ++s) {
        const float* wp = ((col < 64) ? (mu_w1 + (size_t)col*128)
                                      : (vol_w1 + (size_t)(col-64)*128)) + s*32 + q*8;
        float4 f0 = *(const float4*)wp;
        float4 f1 = *(const float4*)(wp + 4);
        float v[8] = {f0.x,f0.y,f0.z,f0.w,f1.x,f1.y,f1.z,f1.w};
        bf16x8 hi, lo;
        #pragma unroll
        for (int j = 0; j < 8; ++j) {
            bf16 hb = (bf16)v[j]; hi[j] = hb; lo[j] = (bf16)(v[j] - (float)hb);
        }
        wbh2[s] = hi; wbl2[s] = lo;
    }

    for (int i = tid; i < 2048; i += 512) {
        int rr = i >> 7, d = i & 127;
        float v = ctxf[(size_t)r0*128 + i];
        g1_s[G1IDX(rr, d)] = v;
        int pos = rr*128 + (((d>>3) ^ rr) & 15)*8 + (d & 7);
        bf16 hb = (bf16)v;
        hdh[0][pos] = hb;
        hdl[0][pos] = (bf16)(v - (float)hb);
    }
    for (int i = tid; i < 320; i += 512) { w2m_s[i] = mu_w2[i]; w2v_s[i] = vol_w2[i]; }
    if (tid < 80) step_s[tid] = 0.f;
    if (tid < 16) rvv[tid] = 1.f + rv[r0 + tid];
    __syncthreads();
    float gi0[4], gi1[4], gi2[4];
    #pragma unroll
    for (int g = 0; g < 3; ++g) {
        int n = g*128 + col;
        const float* wr = wih + (size_t)n*133 + 5;
        #pragma unroll
        for (int r = 0; r < 4; ++r) {
            int row = q*4 + r;
            float a = bih[n];
            #pragma unroll 4
            for (int k = 0; k < 128; ++k) a += g1_s[G1IDX(row, k)] * wr[k];
            if (g == 0) gi0[r] = a; else if (g == 1) gi1[r] = a; else gi2[r] = a;
        }
    }
    __syncthreads();

    int cur = 0;
    for (int st = 0; st < HOR; ++st) {
        const int nxt = cur ^ 1;
        {
            bf16x8 ah[4], al[4];
            #pragma unroll
            for (int s = 0; s < 4; ++s) {
                int off = ml*128 + (((s*4 + q) ^ ml) & 15)*8;
                ah[s] = *(const bf16x8*)&hdh[cur][off];
                al[s] = *(const bf16x8*)&hdl[cur][off];
            }
            floatx4 a1 = (floatx4){0,0,0,0}, a2 = (floatx4){0,0,0,0}, a3 = (floatx4){0,0,0,0};
            floatx4 b1 = (floatx4){0,0,0,0}, b2 = (floatx4){0,0,0,0}, b3 = (floatx4){0,0,0,0};
            floatx4 c1 = (floatx4){0,0,0,0}, c2 = (floatx4){0,0,0,0}, c3 = (floatx4){0,0,0,0};
            #pragma unroll
            for (int s = 0; s < 4; ++s) {
                a1 = __builtin_amdgcn_mfma_f32_16x16x32_bf16(ah[s], wbh1[0][s], a1, 0, 0, 0);
                a2 = __builtin_amdgcn_mfma_f32_16x16x32_bf16(ah[s], wbl1[0][s], a2, 0, 0, 0);
                a3 = __builtin_amdgcn_mfma_f32_16x16x32_bf16(al[s], wbh1[0][s], a3, 0, 0, 0);
                b1 = __builtin_amdgcn_mfma_f32_16x16x32_bf16(ah[s], wbh1[1][s], b1, 0, 0, 0);
                b2 = __builtin_amdgcn_mfma_f32_16x16x32_bf16(ah[s], wbl1[1][s], b2, 0, 0, 0);
                b3 = __builtin_amdgcn_mfma_f32_16x16x32_bf16(al[s], wbh1[1][s], b3, 0, 0, 0);
                c1 = __builtin_amdgcn_mfma_f32_16x16x32_bf16(ah[s], wbh1[2][s], c1, 0, 0, 0);
                c2 = __builtin_amdgcn_mfma_f32_16x16x32_bf16(ah[s], wbl1[2][s], c2, 0, 0, 0);
                c3 = __builtin_amdgcn_mfma_f32_16x16x32_bf16(al[s], wbh1[2][s], c3, 0, 0, 0);
            }
            floatx4 ar = a1 + a2 + a3;
            floatx4 az = b1 + b2 + b3;
            floatx4 an = c1 + c2 + c3;
            #pragma unroll
            for (int r = 0; r < 4; ++r) {
                int row = q*4 + r;
                float ir = gi0[r], iz = gi1[r], in_ = gi2[r];
                #pragma unroll
                for (int j = 0; j < 5; ++j) {
                    float sv = step_s[row*5 + j];
                    ir  += sv * w50[j];
                    iz  += sv * w51[j];
                    in_ += sv * w52[j];
                }
                float rg = fast_sigmoid(ir + ar[r] + bhh0);
                float zg = fast_sigmoid(iz + az[r] + bhh1);
                float nn = fast_tanh(in_ + rg*(an[r] + bhh2));
                int pos = row*128 + (((col>>3) ^ row) & 15)*8 + (col & 7);
                float hold = (float)hdh[cur][pos] + (float)hdl[cur][pos];
                float hnew = (1.f - zg)*nn + zg*hold;
                bf16 hb = (bf16)hnew;
                hdh[nxt][pos] = hb;
                hdl[nxt][pos] = (bf16)(hnew - (float)hb);
            }
        }
        __syncthreads();
        {
            bf16x8 ah[4], al[4];
            #pragma unroll
            for (int s = 0; s < 4; ++s) {
                int off = ml*128 + (((s*4 + q) ^ ml) & 15)*8;
                ah[s] = *(const bf16x8*)&hdh[nxt][off];
                al[s] = *(const bf16x8*)&hdl[nxt][off];
            }
            floatx4 d1 = (floatx4){0,0,0,0}, d2 = (floatx4){0,0,0,0}, d3 = (floatx4){0,0,0,0};
            #pragma unroll
            for (int s = 0; s < 4; ++s) {
                d1 = __builtin_amdgcn_mfma_f32_16x16x32_bf16(ah[s], wbh2[s], d1, 0, 0, 0);
                d2 = __builtin_amdgcn_mfma_f32_16x16x32_bf16(ah[s], wbl2[s], d2, 0, 0, 0);
                d3 = __builtin_amdgcn_mfma_f32_16x16x32_bf16(al[s], wbh2[s], d3, 0, 0, 0);
            }
            floatx4 a4 = d1 + d2 + d3;
            #pragma unroll
            for (int r = 0; r < 4; ++r) {
                float u = a4[r] + bias2;
                g1_s[G1IDX(q*4 + r, col)] = 0.5f*u*(1.f + erff(u*0.70710678118654752f));
            }
        }
        __syncthreads();
        if (tid < 320) {
            int g = tid >> 2;
            int sub = tid & 3;
            int head = sub >> 1, half = sub & 1;
            int rr = g / 5, o = g % 5;
            const float* w2 = head ? w2v_s : w2m_s;
            int wb = o*64 + half*32;
            int gb = head*64 + half*32;
            float s = 0.f;
            #pragma unroll 8
            for (int j = 0; j < 32; ++j)
                s += g1_s[G1IDX(rr, gb + j)] * w2[wb + j];
            s += __shfl_xor(s, 1);
            float resv;
            if (head == 0) resv = fast_tanh(s + mu_b2[o]);
            else {
                float av = s + vol_b2[o];
                float sp = (av > 20.f) ? av : __logf(1.f + __expf(av));
                resv = sp * rvv[rr];
            }
            float other = __shfl_xor(resv, 2);
            if (sub == 0) {
                float pr = resv * other;
                step_s[g] = pr;
                out[((size_t)(r0 + rr)*HOR + st)*MM + o] = pr;
            }
        }
        __syncthreads();
        cur = nxt;
    }
}

// ---------------------------------------------------------------------------
extern "C" void kernel_launch(void* const* d_in, const int* in_sizes, int n_in,
                              void* d_out, int out_size, void* d_ws, size_t ws_size,
                              hipStream_t stream)
{
    (void)in_sizes; (void)n_in; (void)out_size;
    const float* x        = (const float*)d_in[0];
    const int*   sym_id   = (const int*)d_in[1];
    const int*   regime_id= (const int*)d_in[2];
    const float* sym_emb  = (const float*)d_in[3];
    const float* reg_emb  = (const float*)d_in[4];
    const float* in_w     = (const float*)d_in[5];
    const float* in_b     = (const float*)d_in[6];
    const float* qkv_w    = (const float*)d_in[7];
    const float* qkv_b    = (const float*)d_in[8];
    const float* out_w    = (const float*)d_in[9];
    const float* out_bv   = (const float*)d_in[10];
    const float* ln1_w    = (const float*)d_in[11];
    const float* ln1_b    = (const float*)d_in[12];
    const float* ln2_w    = (const float*)d_in[13];
    const float* ln2_b    = (const float*)d_in[14];
    const float* f1_w     = (const float*)d_in[15];
    const float* f1_b     = (const float*)d_in[16];
    const float* f2_w     = (const float*)d_in[17];
    const float* f2_b     = (const float*)d_in[18];
    const float* pool_w   = (const float*)d_in[19];
    const float* pool_b   = (const float*)d_in[20];
    const float* ctx_w    = (const float*)d_in[21];
    const float* ctx_b    = (const float*)d_in[22];
    const float* gru_wih  = (const float*)d_in[23];
    const float* gru_whh  = (const float*)d_in[24];
    const float* gru_bih  = (const float*)d_in[25];
    const float* gru_bhh  = (const float*)d_in[26];
    const float* mu_w1    = (const float*)d_in[27];
    const float* mu_b1    = (const float*)d_in[28];
    const float* mu_w2    = (const float*)d_in[29];
    const float* mu_b2    = (const float*)d_in[30];
    const float* vol_w1   = (const float*)d_in[31];
    const float* vol_b1   = (const float*)d_in[32];
    const float* vol_w2   = (const float*)d_in[33];
    const float* vol_b2   = (const float*)d_in[34];
    float* outp = (float*)d_out;

    char* ws = (char*)d_ws;
    size_t off = 0;
    auto alloc = [&](size_t bytes) -> void* {
        void* p = ws + off;
        off = (off + bytes + 255) & ~(size_t)255;
        return p;
    };
    float* h    = (float*)alloc((size_t)NROWS*DD*4);
    bf16*  y    = (bf16*) alloc((size_t)NROWS*DD*2);
    bf16*  wbf  = (bf16*) alloc((size_t)393216*2);
    float* ctxf = (float*)alloc((size_t)BB*DD*4);
    float* rv   = (float*)alloc((size_t)BB*4);
    // big holds qkv (94.4MB full); chunk rows if workspace is short
    size_t avail = (ws_size > off) ? (ws_size - off) : 0;
    int nch;
    if      (avail >= (size_t)NROWS*384*2)     nch = 1;
    else if (avail >= (size_t)NROWS/2*384*2)   nch = 2;
    else                                       nch = 4;
    const int RC = NROWS / nch;
    const int BC = BB / nch;
    bf16* big = (bf16*)(ws + off);

    prep_weights<<<1536, 256, 0, stream>>>(qkv_w, out_w, f1_w, f2_w, wbf);
    inproj3<<<NROWS/4, 256, 0, stream>>>(x, sym_id, sym_emb, in_w, in_b,
                                         ln1_w, ln1_b, h, y);

    for (int l = 0; l < 2; ++l) {
        const bf16* wqkv = wbf + l*49152;
        const bf16* wout = wbf + 98304 + l*16384;
        const bf16* wf1  = wbf + 131072 + l*65536;
        const bf16* wf2  = wbf + 262144 + l*65536;
        for (int c = 0; c < nch; ++c) {
            const size_t ro = (size_t)c*RC;
            gemm64<0><<<dim3(RC/128, 3), 256, 0, stream>>>(
                y + ro*DD, wqkv, qkv_b + l*384, nullptr, big,
                nullptr, nullptr, nullptr, 384, 128);
            attn_b16<<<BC*4, 256, 0, stream>>>(big, y + ro*DD);
        }
        gemm64<3><<<dim3(NROWS/128, 1), 256, 0, stream>>>(
            y, wout, out_bv + l*128, h, h, ln2_w + l*128, ln2_b + l*128, y, 128, 128);
        if (l == 0)
            ffn_fused<1><<<NROWS/64, 256, 0, stream>>>(
                y, wf1, f1_b, wf2, f2_b, h, ln1_w + 128, ln1_b + 128, y);
        else
            ffn_fused<0><<<NROWS/64, 256, 0, stream>>>(
                y, wf1, f1_b + 512, wf2, f2_b + 128, h, nullptr, nullptr, y);
    }

    pool_ctx3<<<BB, 128, 0, stream>>>(h, x, sym_id, regime_id, sym_emb, reg_emb,
                                      pool_w, pool_b, ctx_w, ctx_b, ctxf, rv);
    gru5_kernel<<<64, 512, 0, stream>>>(ctxf, gru_wih, gru_bih, gru_whh, gru_bhh,
                                        mu_w1, mu_b1, mu_w2, mu_b2,
                                        vol_w1, vol_b1, vol_w2, vol_b2,
                                        rv, outp);
}

// Round 13
// 1297.465 us; speedup vs baseline: 1.4239x; 1.0461x over previous
//
#include <hip/hip_runtime.h>
#include <math.h>

typedef __bf16 bf16;
typedef __bf16 bf16x8 __attribute__((ext_vector_type(8)));
typedef __bf16 bf16x2 __attribute__((ext_vector_type(2)));
typedef float  floatx4 __attribute__((ext_vector_type(4)));

// dims
#define BB 1024
#define TT 120
#define FF 32
#define DD 128
#define NROWS (BB*TT)      // 122880
#define HOR 90
#define MM 5

__device__ __forceinline__ float fast_sigmoid(float x) {
    x = fminf(fmaxf(x, -30.f), 30.f);
    return 1.f / (1.f + __expf(-x));
}
__device__ __forceinline__ float fast_tanh(float x) {
    x = fminf(fmaxf(x, -15.f), 15.f);
    float e = __expf(-2.f * x);
    return (1.f - e) / (1.f + e);
}

// ---------------------------------------------------------------------------
// Encoder weights -> bf16.
__global__ __launch_bounds__(256) void prep_weights(
    const float* __restrict__ qkv, const float* __restrict__ outw,
    const float* __restrict__ f1,  const float* __restrict__ f2,
    bf16* __restrict__ dst)
{
    int i = blockIdx.x*256 + threadIdx.x;
    if (i >= 393216) return;
    float v;
    if      (i < 98304)  v = qkv[i];
    else if (i < 131072) v = outw[i - 98304];
    else if (i < 262144) v = f1[i - 131072];
    else                 v = f2[i - 262144];
    dst[i] = (bf16)v;
}

// ---------------------------------------------------------------------------
// Input projection + PE + fused ln1(L0). 4 rows/block, one wave per row.
// h is bf16 now (fp32 in-register).
__global__ __launch_bounds__(256) void inproj3(
    const float* __restrict__ x, const int* __restrict__ sym_id,
    const float* __restrict__ sym_emb, const float* __restrict__ in_w,
    const float* __restrict__ in_b, const float* __restrict__ lnw,
    const float* __restrict__ lnb, bf16* __restrict__ h, bf16* __restrict__ y)
{
    __shared__ float xin[4][48];
    const int tid = threadIdx.x, lane = tid & 63, wave = tid >> 6;
    const int row0 = blockIdx.x * 4;
    if (tid < 192) {
        int rr = tid / 48, k = tid % 48;
        int row = row0 + rr;
        int b = row / TT;
        xin[rr][k] = (k < 32) ? x[(size_t)row*FF + k]
                              : sym_emb[(size_t)sym_id[b]*16 + (k - 32)];
    }
    __syncthreads();
    const int row = row0 + wave;
    const int t = row % TT;
    const int d0 = lane*2;
    float a0 = in_b[d0], a1 = in_b[d0+1];
    const float* w0 = in_w + (size_t)d0*48;
    const float* w1 = w0 + 48;
    #pragma unroll 8
    for (int k = 0; k < 48; ++k) {
        float xv = xin[wave][k];
        a0 += xv * w0[k];
        a1 += xv * w1[k];
    }
    const float f = expf((float)d0 * (-9.210340371976184f / 128.f));
    const float arg = (float)t * f;
    a0 += sinf(arg);
    a1 += cosf(arg);
    bf16x2 hv = {(bf16)a0, (bf16)a1};
    *(bf16x2*)&h[(size_t)row*DD + d0] = hv;
    float s = a0 + a1, ss = a0*a0 + a1*a1;
    #pragma unroll
    for (int o = 1; o < 64; o <<= 1) { s += __shfl_xor(s, o); ss += __shfl_xor(ss, o); }
    float mean = s * (1.f/128.f);
    float var  = ss * (1.f/128.f) - mean*mean;
    float rstd = rsqrtf(var + 1e-5f);
    bf16x2 o2 = {(bf16)((a0 - mean)*rstd*lnw[d0]   + lnb[d0]),
                 (bf16)((a1 - mean)*rstd*lnw[d0+1] + lnb[d0+1])};
    *(bf16x2*)&y[(size_t)row*DD + d0] = o2;
}

// ---------------------------------------------------------------------------
// bf16 MFMA GEMM, BK=64 (proven R10). EPI: 0 bias->bf16, 1 bias+relu->bf16,
// 2 bias+res->bf16 h, 3 bias+res->bf16 h AND fused row-LN->bf16 (N==128).
template<int EPI>
__global__ __launch_bounds__(256) void gemm64(
    const bf16* __restrict__ A, const bf16* __restrict__ W,
    const float* __restrict__ bias, const bf16* __restrict__ res,
    bf16* __restrict__ outp, const float* __restrict__ lnw,
    const float* __restrict__ lnb, bf16* __restrict__ yout, int N, int K)
{
    __shared__ alignas(16) bf16 As[128*64];
    __shared__ alignas(16) bf16 Ws[128*64];
    __shared__ float psum[2][128];
    __shared__ float psq[2][128];
    const int tid = threadIdx.x;
    const int lane = tid & 63, wave = tid >> 6;
    const int q = lane >> 4, ml = lane & 15;
    const int wm = (wave & 1) * 64, wn = (wave >> 1) * 64;
    const int m0 = blockIdx.x * 128, n0 = blockIdx.y * 128;
    floatx4 acc[4][4];
    #pragma unroll
    for (int i = 0; i < 4; ++i)
        #pragma unroll
        for (int j = 0; j < 4; ++j) acc[i][j] = (floatx4){0.f,0.f,0.f,0.f};
    const int nkb = K >> 6;
    for (int kb = 0; kb < nkb; ++kb) {
        #pragma unroll
        for (int i = 0; i < 4; ++i) {
            int idx = i*256 + tid;
            int r = idx >> 3, c = idx & 7;
            int sw = ((c ^ (r & 7)) * 8);
            *(uint4*)&As[r*64 + sw] = *(const uint4*)(A + (size_t)(m0 + r)*K + kb*64 + c*8);
            *(uint4*)&Ws[r*64 + sw] = *(const uint4*)(W + (size_t)(n0 + r)*K + kb*64 + c*8);
        }
        __syncthreads();
        #pragma unroll
        for (int s = 0; s < 2; ++s) {
            bf16x8 af[4], bfr[4];
            #pragma unroll
            for (int t = 0; t < 4; ++t) {
                int ra = wm + t*16 + ml;
                af[t]  = *(const bf16x8*)&As[ra*64 + (((s*4+q) ^ (ra & 7))*8)];
                int rb = wn + t*16 + ml;
                bfr[t] = *(const bf16x8*)&Ws[rb*64 + (((s*4+q) ^ (rb & 7))*8)];
            }
            #pragma unroll
            for (int i = 0; i < 4; ++i)
                #pragma unroll
                for (int j = 0; j < 4; ++j)
                    acc[i][j] = __builtin_amdgcn_mfma_f32_16x16x32_bf16(af[i], bfr[j], acc[i][j], 0, 0, 0);
        }
        __syncthreads();
    }
    #pragma unroll
    for (int j = 0; j < 4; ++j) {
        int col = n0 + wn + j*16 + ml;
        float bv = bias[col];
        #pragma unroll
        for (int i = 0; i < 4; ++i) {
            #pragma unroll
            for (int r = 0; r < 4; ++r) {
                int row = m0 + wm + i*16 + q*4 + r;
                size_t o = (size_t)row * N + col;
                float v = acc[i][j][r] + bv;
                if      (EPI == 0) outp[o] = (bf16)v;
                else if (EPI == 1) outp[o] = (bf16)fmaxf(v, 0.f);
                else {
                    v += (float)res[o];
                    outp[o] = (bf16)v;
                    acc[i][j][r] = v;          // fp32 value kept for fused LN
                }
            }
        }
    }
    if (EPI == 3) {
        float lw[4], lb[4];
        #pragma unroll
        for (int j = 0; j < 4; ++j) { int col = wn + j*16 + ml; lw[j] = lnw[col]; lb[j] = lnb[col]; }
        #pragma unroll
        for (int i = 0; i < 4; ++i)
            #pragma unroll
            for (int r = 0; r < 4; ++r) {
                float s  = acc[i][0][r] + acc[i][1][r] + acc[i][2][r] + acc[i][3][r];
                float ss = acc[i][0][r]*acc[i][0][r] + acc[i][1][r]*acc[i][1][r]
                         + acc[i][2][r]*acc[i][2][r] + acc[i][3][r]*acc[i][3][r];
                #pragma unroll
                for (int o = 1; o < 16; o <<= 1) { s += __shfl_xor(s, o); ss += __shfl_xor(ss, o); }
                if (ml == 0) {
                    int row = wm + i*16 + q*4 + r;
                    psum[wn >> 6][row] = s;
                    psq [wn >> 6][row] = ss;
                }
            }
        __syncthreads();
        #pragma unroll
        for (int i = 0; i < 4; ++i)
            #pragma unroll
            for (int r = 0; r < 4; ++r) {
                int row = wm + i*16 + q*4 + r;
                float mean = (psum[0][row] + psum[1][row]) * (1.f/128.f);
                float var  = (psq[0][row] + psq[1][row]) * (1.f/128.f) - mean*mean;
                float rstd = rsqrtf(var + 1e-5f);
                #pragma unroll
                for (int j = 0; j < 4; ++j) {
                    int col = wn + j*16 + ml;
                    yout[(size_t)(m0 + row)*128 + col] =
                        (bf16)((acc[i][j][r] - mean)*rstd*lw[j] + lb[j]);
                }
            }
    }
}

// ---------------------------------------------------------------------------
// Fused FFN v2 (proven R12): interleaved halves, 80KB LDS -> 2 blocks/CU.
// h (bf16) += W2 @ relu(W1 @ y + b1) + b2. LNFUSE=1: also y = rowLN(h).
template<int LNFUSE>
__global__ __launch_bounds__(256) void ffn_fused(
    const bf16* __restrict__ y, const bf16* __restrict__ W1,
    const float* __restrict__ b1, const bf16* __restrict__ W2,
    const float* __restrict__ b2, bf16* __restrict__ h,
    const float* __restrict__ lnw, const float* __restrict__ lnb,
    bf16* __restrict__ yout)
{
    __shared__ alignas(16) bf16 ys[64*128];      // 16KB
    __shared__ alignas(16) bf16 mid[2][64*128];  // 32KB
    __shared__ alignas(16) bf16 wbuf[128*128];   // 32KB -> 80KB total
    const int tid = threadIdx.x;
    const int lane = tid & 63, wave = tid >> 6;   // 4 waves
    const int q = lane >> 4, ml = lane & 15;
    const int wm = wave * 16;
    const int m0 = blockIdx.x * 64;
    #pragma unroll
    for (int i = 0; i < 4; ++i) {
        int idx = i*256 + tid;
        int r = idx >> 4, cc = idx & 15;
        *(uint4*)&ys[r*128 + ((cc ^ (r & 15))*8)] =
            *(const uint4*)(y + (size_t)(m0 + r)*128 + cc*8);
    }
    floatx4 acc2[8];
    #pragma unroll
    for (int j = 0; j < 8; ++j) acc2[j] = (floatx4){0.f,0.f,0.f,0.f};
    for (int half = 0; half < 2; ++half) {
        for (int j2 = 0; j2 < 2; ++j2) {
            int nb = half*2 + j2;
            __syncthreads();
            #pragma unroll
            for (int i = 0; i < 8; ++i) {
                int idx = i*256 + tid;
                int r = idx >> 4, cc = idx & 15;
                *(uint4*)&wbuf[r*128 + ((cc ^ (r & 15))*8)] =
                    *(const uint4*)(W1 + (size_t)(nb*128 + r)*128 + cc*8);
            }
            __syncthreads();
            bf16x8 af[4];
            #pragma unroll
            for (int s = 0; s < 4; ++s) {
                int ra = wm + ml;
                af[s] = *(const bf16x8*)&ys[ra*128 + (((4*s+q) ^ (ra & 15))*8)];
            }
            #pragma unroll
            for (int j = 0; j < 8; ++j) {
                floatx4 acc = (floatx4){0.f,0.f,0.f,0.f};
                #pragma unroll
                for (int s = 0; s < 4; ++s) {
                    int rb = j*16 + ml;
                    bf16x8 bfr = *(const bf16x8*)&wbuf[rb*128 + (((4*s+q) ^ (rb & 15))*8)];
                    acc = __builtin_amdgcn_mfma_f32_16x16x32_bf16(af[s], bfr, acc, 0, 0, 0);
                }
                int col = j*16 + ml;
                float bv = b1[nb*128 + col];
                #pragma unroll
                for (int r = 0; r < 4; ++r) {
                    int row = wm + q*4 + r;
                    float v = fmaxf(acc[r] + bv, 0.f);
                    mid[j2][row*128 + (((col>>3) ^ (row & 15))*8) + (col & 7)] = (bf16)v;
                }
            }
        }
        for (int j2 = 0; j2 < 2; ++j2) {
            int kb = half*2 + j2;
            __syncthreads();
            #pragma unroll
            for (int i = 0; i < 8; ++i) {
                int idx = i*256 + tid;
                int r = idx >> 4, cc = idx & 15;
                *(uint4*)&wbuf[r*128 + ((cc ^ (r & 15))*8)] =
                    *(const uint4*)(W2 + (size_t)r*512 + kb*128 + cc*8);
            }
            __syncthreads();
            bf16x8 af[4];
            #pragma unroll
            for (int s = 0; s < 4; ++s) {
                int ra = wm + ml;
                af[s] = *(const bf16x8*)&mid[j2][ra*128 + (((4*s+q) ^ (ra & 15))*8)];
            }
            #pragma unroll
            for (int j = 0; j < 8; ++j) {
                #pragma unroll
                for (int s = 0; s < 4; ++s) {
                    int rb = j*16 + ml;
                    bf16x8 bfr = *(const bf16x8*)&wbuf[rb*128 + (((4*s+q) ^ (rb & 15))*8)];
                    acc2[j] = __builtin_amdgcn_mfma_f32_16x16x32_bf16(af[s], bfr, acc2[j], 0, 0, 0);
                }
            }
        }
    }
    float vr[8][4];
    #pragma unroll
    for (int j = 0; j < 8; ++j) {
        int col = j*16 + ml;
        float bv = b2[col];
        #pragma unroll
        for (int r = 0; r < 4; ++r) {
            int row = wm + q*4 + r;
            size_t o = (size_t)(m0 + row)*128 + col;
            float v = acc2[j][r] + bv + (float)h[o];
            h[o] = (bf16)v;
            vr[j][r] = v;
        }
    }
    if (LNFUSE) {
        float lw[8], lb[8];
        #pragma unroll
        for (int j = 0; j < 8; ++j) { lw[j] = lnw[j*16 + ml]; lb[j] = lnb[j*16 + ml]; }
        #pragma unroll
        for (int r = 0; r < 4; ++r) {
            float s = 0.f, ss = 0.f;
            #pragma unroll
            for (int j = 0; j < 8; ++j) { s += vr[j][r]; ss += vr[j][r]*vr[j][r]; }
            #pragma unroll
            for (int o = 1; o < 16; o <<= 1) { s += __shfl_xor(s, o); ss += __shfl_xor(ss, o); }
            float mean = s * (1.f/128.f);
            float var  = ss * (1.f/128.f) - mean*mean;
            float rstd = rsqrtf(var + 1e-5f);
            int row = wm + q*4 + r;
            #pragma unroll
            for (int j = 0; j < 8; ++j)
                yout[(size_t)(m0 + row)*128 + j*16 + ml] =
                    (bf16)((vr[j][r] - mean)*rstd*lw[j] + lb[j]);
        }
    }
}

// ---------------------------------------------------------------------------
// bf16 MFMA attention v2 (proven R12). One block per (b,h).
__global__ __launch_bounds__(256) void attn_b16(
    const bf16* __restrict__ qkv, bf16* __restrict__ O)
{
    __shared__ alignas(16) bf16 Ks[128*32];
    __shared__ alignas(16) bf16 VT[32*128];
    __shared__ float Sf[64*132];
    const int tid = threadIdx.x, lane = tid & 63, wave = tid >> 6;
    const int q = lane >> 4, ml = lane & 15;
    const int b = blockIdx.x >> 2, hh = blockIdx.x & 3;
    const bf16* base = qkv + (size_t)b*TT*384 + hh*32;
    #pragma unroll
    for (int i = 0; i < 2; ++i) {
        int idx = i*256 + tid;
        int r = idx >> 2, cc = idx & 3;
        uint4 vk = {0,0,0,0};
        if (r < TT) vk = *(const uint4*)(base + (size_t)r*384 + 128 + cc*8);
        int cs = cc ^ ((r >> 1) & 3);
        *(uint4*)&Ks[r*32 + cs*8] = vk;
    }
    {
        int e = tid >> 3, t = 120 + (tid & 7);
        VT[e*128 + (((t >> 3) ^ (e & 15))*8) + (t & 7)] = (bf16)0.f;
    }
    #pragma unroll
    for (int i = 0; i < 2; ++i) {
        int idx = i*256 + tid;
        if (idx < 480) {
            int t = idx >> 2, c = idx & 3;
            uint4 vv = *(const uint4*)(base + (size_t)t*384 + 256 + c*8);
            bf16 tmp[8];
            *(uint4*)tmp = vv;
            #pragma unroll
            for (int jj = 0; jj < 8; ++jj) {
                int e = c*8 + jj;
                VT[e*128 + (((t >> 3) ^ (e & 15))*8) + (t & 7)] = tmp[jj];
            }
        }
    }
    __syncthreads();
    const float scale = 0.17677669529663687f;
    for (int hf = 0; hf < 2; ++hf) {
        {
            int rowa = hf*64 + wave*16 + ml;
            bf16x8 af;
            #pragma unroll
            for (int j = 0; j < 8; ++j) af[j] = (bf16)0.f;
            if (rowa < TT) af = *(const bf16x8*)(base + (size_t)rowa*384 + q*8);
            #pragma unroll
            for (int ni = 0; ni < 8; ++ni) {
                int rowb = ni*16 + ml;
                bf16x8 bfr = *(const bf16x8*)&Ks[rowb*32 + ((q ^ ((rowb>>1)&3))*8)];
                floatx4 a4 = __builtin_amdgcn_mfma_f32_16x16x32_bf16(
                    af, bfr, (floatx4){0.f,0.f,0.f,0.f}, 0, 0, 0);
                #pragma unroll
                for (int r = 0; r < 4; ++r)
                    Sf[(wave*16 + q*4 + r)*132 + ni*16 + ml] = a4[r]*scale;
            }
        }
        __syncthreads();
        {
            int rl = wave*16 + (lane >> 2);
            int part = lane & 3;
            int rg = hf*64 + rl;
            if (rg < TT) {
                float* rowp = &Sf[rl*132 + part*30];
                float mx = -3e38f;
                #pragma unroll 10
                for (int j = 0; j < 30; ++j) mx = fmaxf(mx, rowp[j]);
                mx = fmaxf(mx, __shfl_xor(mx, 1));
                mx = fmaxf(mx, __shfl_xor(mx, 2));
                float sm = 0.f;
                #pragma unroll 10
                for (int j = 0; j < 30; ++j) sm += __expf(rowp[j] - mx);
                sm += __shfl_xor(sm, 1);
                sm += __shfl_xor(sm, 2);
                float inv = 1.f / sm;
                #pragma unroll 10
                for (int j = 0; j < 30; ++j) rowp[j] = __expf(rowp[j] - mx) * inv;
                if (part == 3) {
                    #pragma unroll
                    for (int c = 120; c < 128; ++c) Sf[rl*132 + c] = 0.f;
                }
            }
        }
        __syncthreads();
        floatx4 pacc[2];
        pacc[0] = (floatx4){0.f,0.f,0.f,0.f};
        pacc[1] = (floatx4){0.f,0.f,0.f,0.f};
        #pragma unroll
        for (int s = 0; s < 4; ++s) {
            const float* pr = &Sf[(wave*16 + ml)*132 + 32*s + 8*q];
            float4 p0 = *(const float4*)pr;
            float4 p1 = *(const float4*)(pr + 4);
            bf16x8 af2 = {(bf16)p0.x,(bf16)p0.y,(bf16)p0.z,(bf16)p0.w,
                          (bf16)p1.x,(bf16)p1.y,(bf16)p1.z,(bf16)p1.w};
            #pragma unroll
            for (int nv = 0; nv < 2; ++nv) {
                int e = nv*16 + ml;
                bf16x8 bfr = *(const bf16x8*)&VT[e*128 + ((((4*s+q) ^ (e & 15)))*8)];
                pacc[nv] = __builtin_amdgcn_mfma_f32_16x16x32_bf16(af2, bfr, pacc[nv], 0, 0, 0);
            }
        }
        #pragma unroll
        for (int nv = 0; nv < 2; ++nv)
            #pragma unroll
            for (int r = 0; r < 4; ++r) {
                int row = hf*64 + wave*16 + q*4 + r;
                if (row < TT)
                    O[((size_t)b*TT + row)*DD + hh*32 + nv*16 + ml] = (bf16)pacc[nv][r];
            }
        __syncthreads();
    }
}

// ---------------------------------------------------------------------------
// Pool+ctx+rv; h is bf16 now.
__global__ __launch_bounds__(128) void pool_ctx3(
    const bf16* __restrict__ h, const float* __restrict__ x,
    const int* __restrict__ sym_id, const int* __restrict__ regime_id,
    const float* __restrict__ sym_emb, const float* __restrict__ reg_emb,
    const float* __restrict__ pool_w, const float* __restrict__ pool_b,
    const float* __restrict__ ctx_w, const float* __restrict__ ctx_b,
    float* __restrict__ ctxf, float* __restrict__ rv)
{
    __shared__ float sc[120];
    __shared__ float aw[120];
    __shared__ float cat[152];
    const int b = blockIdx.x;
    const int tid = threadIdx.x, lane = tid & 63, wave = tid >> 6;
    const bf16* hb = h + (size_t)b*TT*DD;
    for (int t = wave*60; t < wave*60 + 60; ++t) {
        bf16x2 v = *(const bf16x2*)(hb + (size_t)t*DD + lane*2);
        float s = (float)v[0] * pool_w[lane*2] + (float)v[1] * pool_w[lane*2 + 1];
        #pragma unroll
        for (int o = 1; o < 64; o <<= 1) s += __shfl_xor(s, o);
        if (lane == 0) sc[t] = s + pool_b[0];
    }
    __syncthreads();
    if (wave == 0) {
        float v0 = sc[lane];
        float v1 = (lane < 56) ? sc[lane + 64] : -3e38f;
        float mx = fmaxf(v0, v1);
        #pragma unroll
        for (int o = 1; o < 64; o <<= 1) mx = fmaxf(mx, __shfl_xor(mx, o));
        float e0 = expf(v0 - mx);
        float e1 = (lane < 56) ? expf(v1 - mx) : 0.f;
        float sm = e0 + e1;
        #pragma unroll
        for (int o = 1; o < 64; o <<= 1) sm += __shfl_xor(sm, o);
        float inv = 1.f / sm;
        aw[lane] = e0 * inv;
        if (lane < 56) aw[lane + 64] = e1 * inv;
    } else {
        float v0 = x[((size_t)b*TT + lane)*FF];
        float v1 = (lane < 56) ? x[((size_t)b*TT + lane + 64)*FF] : 0.f;
        float s = v0 + v1;
        #pragma unroll
        for (int o = 1; o < 64; o <<= 1) s += __shfl_xor(s, o);
        float mean = s / 120.f;
        float d0 = v0 - mean, d1 = (lane < 56) ? (v1 - mean) : 0.f;
        float ss = d0*d0 + d1*d1;
        #pragma unroll
        for (int o = 1; o < 64; o <<= 1) ss += __shfl_xor(ss, o);
        if (lane == 0) rv[b] = sqrtf(ss / 119.f);
    }
    __syncthreads();
    {
        float p = 0.f;
        for (int t = 0; t < TT; ++t) p += aw[t] * (float)hb[(size_t)t*DD + tid];
        cat[tid] = p;
    }
    if (tid < 16)      cat[128 + tid] = sym_emb[(size_t)sym_id[b]*16 + tid];
    else if (tid < 24) cat[144 + (tid-16)] = reg_emb[regime_id[b]*8 + (tid-16)];
    __syncthreads();
    float acc = ctx_b[tid];
    const float* wr = ctx_w + (size_t)tid*152;
    for (int j = 0; j < 152; ++j) acc += cat[j] * wr[j];
    ctxf[(size_t)b*128 + tid] = acc;
}

// ---------------------------------------------------------------------------
// GRU v5 (proven R9/R11/R12).
#define G1IDX(rr,c) ((rr)*132 + (c) + ((c)>>5))
__global__ __launch_bounds__(512, 1) void gru5_kernel(
    const float* __restrict__ ctxf, const float* __restrict__ wih,
    const float* __restrict__ bih, const float* __restrict__ whh,
    const float* __restrict__ bhh,
    const float* __restrict__ mu_w1, const float* __restrict__ mu_b1,
    const float* __restrict__ mu_w2, const float* __restrict__ mu_b2,
    const float* __restrict__ vol_w1, const float* __restrict__ vol_b1,
    const float* __restrict__ vol_w2, const float* __restrict__ vol_b2,
    const float* __restrict__ rv, float* __restrict__ out)
{
    __shared__ alignas(16) bf16 hdh[2][16*128];
    __shared__ alignas(16) bf16 hdl[2][16*128];
    __shared__ float g1_s[16*132];
    __shared__ float step_s[80];
    __shared__ float w2m_s[320], w2v_s[320];
    __shared__ float rvv[16];
    const int tid = threadIdx.x, lane = tid & 63, wave = tid >> 6;  // 8 waves
    const int q = lane >> 4, ml = lane & 15;
    const int col = wave*16 + ml;
    const int r0 = blockIdx.x * 16;

    bf16x8 wbh1[3][4], wbl1[3][4], wbh2[4], wbl2[4];
    float w50[5], w51[5], w52[5];
    #pragma unroll
    for (int g = 0; g < 3; ++g) {
        int n = g*128 + col;
        #pragma unroll
        for (int s = 0; s < 4; ++s) {
            const float* wp = whh + (size_t)n*128 + s*32 + q*8;
            float4 f0 = *(const float4*)wp;
            float4 f1 = *(const float4*)(wp + 4);
            float v[8] = {f0.x,f0.y,f0.z,f0.w,f1.x,f1.y,f1.z,f1.w};
            bf16x8 hi, lo;
            #pragma unroll
            for (int j = 0; j < 8; ++j) {
                bf16 hb = (bf16)v[j]; hi[j] = hb; lo[j] = (bf16)(v[j] - (float)hb);
            }
            wbh1[g][s] = hi; wbl1[g][s] = lo;
        }
        #pragma unroll
        for (int j = 0; j < 5; ++j) {
            float wv = wih[(size_t)n*133 + j];
            if (g == 0) w50[j] = wv; else if (g == 1) w51[j] = wv; else w52[j] = wv;
        }
    }
    const float bhh0 = bhh[col], bhh1 = bhh[128 + col], bhh2 = bhh[256 + col];
    float bias2 = (col < 64) ? mu_b1[col] : vol_b1[col - 64];
    #pragma unroll
    for (int s = 0; s < 4; ++s) {
        const float* wp = ((col < 64) ? (mu_w1 + (size_t)col*128)
                                      : (vol_w1 + (size_t)(col-64)*128)) + s*32 + q*8;
        float4 f0 = *(const float4*)wp;
        float4 f1 = *(const float4*)(wp + 4);
        float v[8] = {f0.x,f0.y,f0.z,f0.w,f1.x,f1.y,f1.z,f1.w};
        bf16x8 hi, lo;
        #pragma unroll
        for (int j = 0; j < 8; ++j) {
            bf16 hb = (bf16)v[j]; hi[j] = hb; lo[j] = (bf16)(v[j] - (float)hb);
        }
        wbh2[s] = hi; wbl2[s] = lo;
    }

    for (int i = tid; i < 2048; i += 512) {
        int rr = i >> 7, d = i & 127;
        float v = ctxf[(size_t)r0*128 + i];
        g1_s[G1IDX(rr, d)] = v;
        int pos = rr*128 + (((d>>3) ^ rr) & 15)*8 + (d & 7);
        bf16 hb = (bf16)v;
        hdh[0][pos] = hb;
        hdl[0][pos] = (bf16)(v - (float)hb);
    }
    for (int i = tid; i < 320; i += 512) { w2m_s[i] = mu_w2[i]; w2v_s[i] = vol_w2[i]; }
    if (tid < 80) step_s[tid] = 0.f;
    if (tid < 16) rvv[tid] = 1.f + rv[r0 + tid];
    __syncthreads();
    float gi0[4], gi1[4], gi2[4];
    #pragma unroll
    for (int g = 0; g < 3; ++g) {
        int n = g*128 + col;
        const float* wr = wih + (size_t)n*133 + 5;
        #pragma unroll
        for (int r = 0; r < 4; ++r) {
            int row = q*4 + r;
            float a = bih[n];
            #pragma unroll 4
            for (int k = 0; k < 128; ++k) a += g1_s[G1IDX(row, k)] * wr[k];
            if (g == 0) gi0[r] = a; else if (g == 1) gi1[r] = a; else gi2[r] = a;
        }
    }
    __syncthreads();

    int cur = 0;
    for (int st = 0; st < HOR; ++st) {
        const int nxt = cur ^ 1;
        {
            bf16x8 ah[4], al[4];
            #pragma unroll
            for (int s = 0; s < 4; ++s) {
                int off = ml*128 + (((s*4 + q) ^ ml) & 15)*8;
                ah[s] = *(const bf16x8*)&hdh[cur][off];
                al[s] = *(const bf16x8*)&hdl[cur][off];
            }
            floatx4 a1 = (floatx4){0,0,0,0}, a2 = (floatx4){0,0,0,0}, a3 = (floatx4){0,0,0,0};
            floatx4 b1 = (floatx4){0,0,0,0}, b2 = (floatx4){0,0,0,0}, b3 = (floatx4){0,0,0,0};
            floatx4 c1 = (floatx4){0,0,0,0}, c2 = (floatx4){0,0,0,0}, c3 = (floatx4){0,0,0,0};
            #pragma unroll
            for (int s = 0; s < 4; ++s) {
                a1 = __builtin_amdgcn_mfma_f32_16x16x32_bf16(ah[s], wbh1[0][s], a1, 0, 0, 0);
                a2 = __builtin_amdgcn_mfma_f32_16x16x32_bf16(ah[s], wbl1[0][s], a2, 0, 0, 0);
                a3 = __builtin_amdgcn_mfma_f32_16x16x32_bf16(al[s], wbh1[0][s], a3, 0, 0, 0);
                b1 = __builtin_amdgcn_mfma_f32_16x16x32_bf16(ah[s], wbh1[1][s], b1, 0, 0, 0);
                b2 = __builtin_amdgcn_mfma_f32_16x16x32_bf16(ah[s], wbl1[1][s], b2, 0, 0, 0);
                b3 = __builtin_amdgcn_mfma_f32_16x16x32_bf16(al[s], wbh1[1][s], b3, 0, 0, 0);
                c1 = __builtin_amdgcn_mfma_f32_16x16x32_bf16(ah[s], wbh1[2][s], c1, 0, 0, 0);
                c2 = __builtin_amdgcn_mfma_f32_16x16x32_bf16(ah[s], wbl1[2][s], c2, 0, 0, 0);
                c3 = __builtin_amdgcn_mfma_f32_16x16x32_bf16(al[s], wbh1[2][s], c3, 0, 0, 0);
            }
            floatx4 ar = a1 + a2 + a3;
            floatx4 az = b1 + b2 + b3;
            floatx4 an = c1 + c2 + c3;
            #pragma unroll
            for (int r = 0; r < 4; ++r) {
                int row = q*4 + r;
                float ir = gi0[r], iz = gi1[r], in_ = gi2[r];
                #pragma unroll
                for (int j = 0; j < 5; ++j) {
                    float sv = step_s[row*5 + j];
                    ir  += sv * w50[j];
                    iz  += sv * w51[j];
                    in_ += sv * w52[j];
                }
                float rg = fast_sigmoid(ir + ar[r] + bhh0);
                float zg = fast_sigmoid(iz + az[r] + bhh1);
                float nn = fast_tanh(in_ + rg*(an[r] + bhh2));
                int pos = row*128 + (((col>>3) ^ row) & 15)*8 + (col & 7);
                float hold = (float)hdh[cur][pos] + (float)hdl[cur][pos];
                float hnew = (1.f - zg)*nn + zg*hold;
                bf16 hb = (bf16)hnew;
                hdh[nxt][pos] = hb;
                hdl[nxt][pos] = (bf16)(hnew - (float)hb);
            }
        }
        __syncthreads();
        {
            bf16x8 ah[4], al[4];
            #pragma unroll
            for (int s = 0; s < 4; ++s) {
                int off = ml*128 + (((s*4 + q) ^ ml) & 15)*8;
                ah[s] = *(const bf16x8*)&hdh[nxt][off];
                al[s] = *(const bf16x8*)&hdl[nxt][off];
            }
            floatx4 d1 = (floatx4){0,0,0,0}, d2 = (floatx4){0,0,0,0}, d3 = (floatx4){0,0,0,0};
            #pragma unroll
            for (int s = 0; s < 4; ++s) {
                d1 = __builtin_amdgcn_mfma_f32_16x16x32_bf16(ah[s], wbh2[s], d1, 0, 0, 0);
                d2 = __builtin_amdgcn_mfma_f32_16x16x32_bf16(ah[s], wbl2[s], d2, 0, 0, 0);
                d3 = __builtin_amdgcn_mfma_f32_16x16x32_bf16(al[s], wbh2[s], d3, 0, 0, 0);
            }
            floatx4 a4 = d1 + d2 + d3;
            #pragma unroll
            for (int r = 0; r < 4; ++r) {
                float u = a4[r] + bias2;
                g1_s[G1IDX(q*4 + r, col)] = 0.5f*u*(1.f + erff(u*0.70710678118654752f));
            }
        }
        __syncthreads();
        if (tid < 320) {
            int g = tid >> 2;
            int sub = tid & 3;
            int head = sub >> 1, half = sub & 1;
            int rr = g / 5, o = g % 5;
            const float* w2 = head ? w2v_s : w2m_s;
            int wb = o*64 + half*32;
            int gb = head*64 + half*32;
            float s = 0.f;
            #pragma unroll 8
            for (int j = 0; j < 32; ++j)
                s += g1_s[G1IDX(rr, gb + j)] * w2[wb + j];
            s += __shfl_xor(s, 1);
            float resv;
            if (head == 0) resv = fast_tanh(s + mu_b2[o]);
            else {
                float av = s + vol_b2[o];
                float sp = (av > 20.f) ? av : __logf(1.f + __expf(av));
                resv = sp * rvv[rr];
            }
            float other = __shfl_xor(resv, 2);
            if (sub == 0) {
                float pr = resv * other;
                step_s[g] = pr;
                out[((size_t)(r0 + rr)*HOR + st)*MM + o] = pr;
            }
        }
        __syncthreads();
        cur = nxt;
    }
}

// ---------------------------------------------------------------------------
extern "C" void kernel_launch(void* const* d_in, const int* in_sizes, int n_in,
                              void* d_out, int out_size, void* d_ws, size_t ws_size,
                              hipStream_t stream)
{
    (void)in_sizes; (void)n_in; (void)out_size;
    const float* x        = (const float*)d_in[0];
    const int*   sym_id   = (const int*)d_in[1];
    const int*   regime_id= (const int*)d_in[2];
    const float* sym_emb  = (const float*)d_in[3];
    const float* reg_emb  = (const float*)d_in[4];
    const float* in_w     = (const float*)d_in[5];
    const float* in_b     = (const float*)d_in[6];
    const float* qkv_w    = (const float*)d_in[7];
    const float* qkv_b    = (const float*)d_in[8];
    const float* out_w    = (const float*)d_in[9];
    const float* out_bv   = (const float*)d_in[10];
    const float* ln1_w    = (const float*)d_in[11];
    const float* ln1_b    = (const float*)d_in[12];
    const float* ln2_w    = (const float*)d_in[13];
    const float* ln2_b    = (const float*)d_in[14];
    const float* f1_w     = (const float*)d_in[15];
    const float* f1_b     = (const float*)d_in[16];
    const float* f2_w     = (const float*)d_in[17];
    const float* f2_b     = (const float*)d_in[18];
    const float* pool_w   = (const float*)d_in[19];
    const float* pool_b   = (const float*)d_in[20];
    const float* ctx_w    = (const float*)d_in[21];
    const float* ctx_b    = (const float*)d_in[22];
    const float* gru_wih  = (const float*)d_in[23];
    const float* gru_whh  = (const float*)d_in[24];
    const float* gru_bih  = (const float*)d_in[25];
    const float* gru_bhh  = (const float*)d_in[26];
    const float* mu_w1    = (const float*)d_in[27];
    const float* mu_b1    = (const float*)d_in[28];
    const float* mu_w2    = (const float*)d_in[29];
    const float* mu_b2    = (const float*)d_in[30];
    const float* vol_w1   = (const float*)d_in[31];
    const float* vol_b1   = (const float*)d_in[32];
    const float* vol_w2   = (const float*)d_in[33];
    const float* vol_b2   = (const float*)d_in[34];
    float* outp = (float*)d_out;

    char* ws = (char*)d_ws;
    size_t off = 0;
    auto alloc = [&](size_t bytes) -> void* {
        void* p = ws + off;
        off = (off + bytes + 255) & ~(size_t)255;
        return p;
    };
    bf16*  h    = (bf16*) alloc((size_t)NROWS*DD*2);   // 31.5 MB bf16 residual
    bf16*  y    = (bf16*) alloc((size_t)NROWS*DD*2);   // 31.5 MB activations
    bf16*  wbf  = (bf16*) alloc((size_t)393216*2);
    float* ctxf = (float*)alloc((size_t)BB*DD*4);
    float* rv   = (float*)alloc((size_t)BB*4);
    // big holds qkv (94.4MB full); chunk rows if workspace is short
    size_t avail = (ws_size > off) ? (ws_size - off) : 0;
    int nch;
    if      (avail >= (size_t)NROWS*384*2)     nch = 1;
    else if (avail >= (size_t)NROWS/2*384*2)   nch = 2;
    else                                       nch = 4;
    const int RC = NROWS / nch;
    const int BC = BB / nch;
    bf16* big = (bf16*)(ws + off);

    prep_weights<<<1536, 256, 0, stream>>>(qkv_w, out_w, f1_w, f2_w, wbf);
    inproj3<<<NROWS/4, 256, 0, stream>>>(x, sym_id, sym_emb, in_w, in_b,
                                         ln1_w, ln1_b, h, y);

    for (int l = 0; l < 2; ++l) {
        const bf16* wqkv = wbf + l*49152;
        const bf16* wout = wbf + 98304 + l*16384;
        const bf16* wf1  = wbf + 131072 + l*65536;
        const bf16* wf2  = wbf + 262144 + l*65536;
        for (int c = 0; c < nch; ++c) {
            const size_t ro = (size_t)c*RC;
            gemm64<0><<<dim3(RC/128, 3), 256, 0, stream>>>(
                y + ro*DD, wqkv, qkv_b + l*384, nullptr, big,
                nullptr, nullptr, nullptr, 384, 128);
            attn_b16<<<BC*4, 256, 0, stream>>>(big, y + ro*DD);
        }
        gemm64<3><<<dim3(NROWS/128, 1), 256, 0, stream>>>(
            y, wout, out_bv + l*128, h, h, ln2_w + l*128, ln2_b + l*128, y, 128, 128);
        if (l == 0)
            ffn_fused<1><<<NROWS/64, 256, 0, stream>>>(
                y, wf1, f1_b, wf2, f2_b, h, ln1_w + 128, ln1_b + 128, y);
        else
            ffn_fused<0><<<NROWS/64, 256, 0, stream>>>(
                y, wf1, f1_b + 512, wf2, f2_b + 128, h, nullptr, nullptr, y);
    }

    pool_ctx3<<<BB, 128, 0, stream>>>(h, x, sym_id, regime_id, sym_emb, reg_emb,
                                      pool_w, pool_b, ctx_w, ctx_b, ctxf, rv);
    gru5_kernel<<<64, 512, 0, stream>>>(ctxf, gru_wih, gru_bih, gru_whh, gru_bhh,
                                        mu_w1, mu_b1, mu_w2, mu_b2,
                                        vol_w1, vol_b1, vol_w2, vol_b2,
                                        rv, outp);
}